// Round 14
// baseline (844.698 us; speedup 1.0000x reference)
//
#include <hip/hip_runtime.h>
#include <hip/hip_bf16.h>
#include <math.h>

#define Bb 2
#define Ss 2048
#define Dd 1024
#define Hh 16
#define DH 64
#define Ee 8
#define FH 4096
#define Tt (Bb*Ss)

typedef __attribute__((ext_vector_type(8))) short short8;
typedef __attribute__((ext_vector_type(4))) short short4v;
typedef __attribute__((ext_vector_type(4))) float float4v;

static __device__ inline short f2bf(float f) {
    __hip_bfloat16 h = __float2bfloat16(f);
    return *reinterpret_cast<short*>(&h);
}

// async global->LDS, 16B per lane. LDS dest = wave-uniform base + lane*16.
static __device__ inline void glds16(const __hip_bfloat16* g, __hip_bfloat16* l) {
    __builtin_amdgcn_global_load_lds(
        (const __attribute__((address_space(1))) unsigned int*)g,
        (__attribute__((address_space(3))) unsigned int*)l, 16, 0, 0);
}

// ---------------------------------------------------------------------------
// LayerNorm -> bf16. One block (256 thr) per token. (Used only for LN1; LN2
// is fused into gate_kernel.)
__global__ __launch_bounds__(256) void ln_kernel(const float* __restrict__ x,
                                                 const float* __restrict__ sc,
                                                 const float* __restrict__ bi,
                                                 __hip_bfloat16* __restrict__ y) {
    int t = blockIdx.x, tid = threadIdx.x;
    const float* xr = x + (size_t)t * Dd;
    float s1 = 0.f, s2 = 0.f;
    for (int d = tid; d < Dd; d += 256) { float v = xr[d]; s1 += v; s2 += v * v; }
    __shared__ float r1[256], r2[256];
    r1[tid] = s1; r2[tid] = s2; __syncthreads();
    for (int off = 128; off > 0; off >>= 1) {
        if (tid < off) { r1[tid] += r1[tid + off]; r2[tid] += r2[tid + off]; }
        __syncthreads();
    }
    float mu = r1[0] * (1.f / Dd);
    float var = r2[0] * (1.f / Dd) - mu * mu;
    float rstd = rsqrtf(var + 1e-6f);
    __hip_bfloat16* yr = y + (size_t)t * Dd;
    for (int d = tid; d < Dd; d += 256) {
        float v = xr[d];
        yr[d] = __float2bfloat16((v - mu) * rstd * sc[d] + bi[d]);
    }
}

// ---------------------------------------------------------------------------
// Vectorized transpose+convert fp32 [K][N] -> bf16 [N][K]. 64x64 tiles:
// float4 global reads, short4v 8B writes, LDS [64][65] fp32 (pad 65).
__global__ __launch_bounds__(256) void transpose_qkvo(
    const float* W0, const float* W1, const float* W2, const float* W3,
    __hip_bfloat16* T0, __hip_bfloat16* T1, __hip_bfloat16* T2, __hip_bfloat16* T3) {
    int z = blockIdx.z;
    const float* W = (z == 0) ? W0 : (z == 1) ? W1 : (z == 2) ? W2 : W3;
    __hip_bfloat16* Wt = (z == 0) ? T0 : (z == 1) ? T1 : (z == 2) ? T2 : T3;
    __shared__ float tile[64][65];
    int k0 = blockIdx.y * 64, n0 = blockIdx.x * 64;
    int tx = threadIdx.x & 15, ty = threadIdx.x >> 4;
    #pragma unroll
    for (int p = 0; p < 4; p++) {
        float4 v = *(const float4*)(&W[(size_t)(k0 + ty + p * 16) * Dd + n0 + tx * 4]);
        tile[ty + p * 16][tx * 4 + 0] = v.x;
        tile[ty + p * 16][tx * 4 + 1] = v.y;
        tile[ty + p * 16][tx * 4 + 2] = v.z;
        tile[ty + p * 16][tx * 4 + 3] = v.w;
    }
    __syncthreads();
    #pragma unroll
    for (int p = 0; p < 4; p++) {
        int n = ty + p * 16;
        short4v pk;
        pk[0] = f2bf(tile[tx * 4 + 0][n]);
        pk[1] = f2bf(tile[tx * 4 + 1][n]);
        pk[2] = f2bf(tile[tx * 4 + 2][n]);
        pk[3] = f2bf(tile[tx * 4 + 3][n]);
        *(short4v*)(&Wt[(size_t)(n0 + n) * Dd + k0 + tx * 4]) = pk;
    }
}

// Batched expert-weight transpose (vectorized): W[e] fp32 [K][N] -> bf16 [N][K].
__global__ __launch_bounds__(256) void transpose_we(const float* __restrict__ W,
                                                    __hip_bfloat16* __restrict__ Wt,
                                                    int Kd, int N) {
    int e = blockIdx.z;
    W  += (size_t)e * Kd * N;
    Wt += (size_t)e * Kd * N;
    __shared__ float tile[64][65];
    int k0 = blockIdx.y * 64, n0 = blockIdx.x * 64;
    int tx = threadIdx.x & 15, ty = threadIdx.x >> 4;
    #pragma unroll
    for (int p = 0; p < 4; p++) {
        float4 v = *(const float4*)(&W[(size_t)(k0 + ty + p * 16) * N + n0 + tx * 4]);
        tile[ty + p * 16][tx * 4 + 0] = v.x;
        tile[ty + p * 16][tx * 4 + 1] = v.y;
        tile[ty + p * 16][tx * 4 + 2] = v.z;
        tile[ty + p * 16][tx * 4 + 3] = v.w;
    }
    __syncthreads();
    #pragma unroll
    for (int p = 0; p < 4; p++) {
        int n = ty + p * 16;
        short4v pk;
        pk[0] = f2bf(tile[tx * 4 + 0][n]);
        pk[1] = f2bf(tile[tx * 4 + 1][n]);
        pk[2] = f2bf(tile[tx * 4 + 2][n]);
        pk[3] = f2bf(tile[tx * 4 + 3][n]);
        *(short4v*)(&Wt[(size_t)(n0 + n) * Kd + k0 + tx * 4]) = pk;
    }
}

// ---------------------------------------------------------------------------
// bf16 MFMA GEMM, tile 128x128, BK=32, double-buffered global_load_lds staging
// (round-6 verified loop). LDS LINEAR [128][32]/buffer; both-sides slot
// swizzle: LDS (row, s) holds global 16B-slot s ^ ((row>>1)&3).
// __launch_bounds__(256, 4): push to 4 waves/SIMD (4 blocks/CU). At the
// measured 136 regs/wave (72 arch + 64 acc) only 3 fit; capping arch-VGPR at
// 64 buys +33% resident waves for this latency-bound loop.
// MODE 0: plain -> bf16 C
// MODE 1: + residual fp32 -> fp32 C  (Wo)
// MODE 2: expert GEMM1: gather A rows via bucket, gelu -> Hbuf[base[e]+m] bf16
// MODE 3: expert GEMM2: A = H + base[e], fp32 out. NS=2: z=2e+s, split-K
//         halves; s=0 -> Cv (+bias), s=1 -> Cv2 (no bias). combine_out sums.
// MODE 4: V projection -> Vt[b][h][d][s] bf16 (transposed write)
// MODE 5: fused QKV: z in {0,1,2}; Bt += z*D*D; bias={bias,bias_k,bias_v}[z];
//         out: z=0->Cv(bf16), z=1->Ck(bf16), z=2->Cv2 (Vt transposed write).
template<int MODE, int NS = 1>
__global__ __launch_bounds__(256, 4) void gemm_mfma(
    const __hip_bfloat16* __restrict__ A, const __hip_bfloat16* __restrict__ Bt,
    const float* __restrict__ bias, void* __restrict__ Cv,
    int M, int N, int Kd,
    const int* __restrict__ bucket, const int* __restrict__ cnts,
    const int* __restrict__ bases, const float* __restrict__ residual,
    const float* __restrict__ bias_k, const float* __restrict__ bias_v,
    void* __restrict__ Ck, void* __restrict__ Cv2)
{
    int Me = M;
    const int* rowIdx = nullptr;
    int hbase = 0;
    int ksplit = 0;
    int zsel = 0;
    if (MODE == 2 || MODE == 3) {
        int e = (NS == 2) ? (blockIdx.z >> 1) : blockIdx.z;
        if (NS == 2) ksplit = blockIdx.z & 1;
        Me = cnts[e];
        hbase = bases[e];
        Bt += (size_t)e * N * Kd;
        bias += (size_t)e * N;
        if (MODE == 2) rowIdx = bucket + e * Tt;
        if (MODE == 3) A += (size_t)hbase * Kd;
    }
    if (MODE == 5) {
        zsel = blockIdx.z;
        Bt += (size_t)zsel * Dd * Dd;
        if (zsel == 1) bias = bias_k;
        if (zsel == 2) bias = bias_v;
    }
    int m0 = blockIdx.y * 128;
    if (m0 >= Me) return;
    int n0 = blockIdx.x * 128;

    __shared__ __hip_bfloat16 As[2 * 128 * 32];
    __shared__ __hip_bfloat16 Bs[2 * 128 * 32];

    int tid = threadIdx.x;
    int lane = tid & 63, wave = tid >> 6;
    int wm = (wave & 1) * 64, wn = (wave >> 1) * 64;
    int quad = lane >> 4, l16 = lane & 15;

    int rs = lane >> 2;
    int sslot = (lane & 3) ^ ((lane >> 3) & 3);
    int rowS0 = 16 * (2 * wave + 0) + rs;
    int rowS1 = 16 * (2 * wave + 1) + rs;

    const __hip_bfloat16 *gA0, *gA1;
    if (MODE == 2) {
        int g0 = m0 + rowS0, g1 = m0 + rowS1;
        int r0 = (g0 < Me) ? rowIdx[g0] : 0;
        int r1 = (g1 < Me) ? rowIdx[g1] : 0;
        gA0 = A + (size_t)r0 * Kd + sslot * 8;
        gA1 = A + (size_t)r1 * Kd + sslot * 8;
    } else {
        gA0 = A + (size_t)(m0 + rowS0) * Kd + sslot * 8;
        gA1 = A + (size_t)(m0 + rowS1) * Kd + sslot * 8;
    }
    const __hip_bfloat16* gB0 = Bt + (size_t)(n0 + rowS0) * Kd + sslot * 8;
    const __hip_bfloat16* gB1 = Bt + (size_t)(n0 + rowS1) * Kd + sslot * 8;

    __hip_bfloat16* lA0 = As + (2 * wave + 0) * 512;
    __hip_bfloat16* lA1 = As + (2 * wave + 1) * 512;
    __hip_bfloat16* lB0 = Bs + (2 * wave + 0) * 512;
    __hip_bfloat16* lB1 = Bs + (2 * wave + 1) * 512;

    int rsw = (l16 >> 1) & 3;
    int rdoff = (quad ^ rsw) * 8;

    float4v acc[4][4];
    #pragma unroll
    for (int i = 0; i < 4; i++)
        #pragma unroll
        for (int j = 0; j < 4; j++) acc[i][j] = (float4v)0.f;

    const int NT = Kd >> 5;
    int t0s = 0, t1s = NT;
    if (NS == 2) { int hlf = NT >> 1; t0s = ksplit * hlf; t1s = t0s + hlf; }

    {
        int ko = t0s << 5;
        glds16(gA0 + ko, lA0);
        glds16(gA1 + ko, lA1);
        glds16(gB0 + ko, lB0);
        glds16(gB1 + ko, lB1);
    }
    __syncthreads();

    int cur = 0;
    for (int t = t0s; t < t1s; t++) {
        if (t + 1 < t1s) {
            int ko = (t + 1) << 5;
            int bo = (cur ^ 1) * 4096;
            glds16(gA0 + ko, lA0 + bo);
            glds16(gA1 + ko, lA1 + bo);
            glds16(gB0 + ko, lB0 + bo);
            glds16(gB1 + ko, lB1 + bo);
        }
        int cb = cur * 4096;
        short8 af[4], bf[4];
        #pragma unroll
        for (int i = 0; i < 4; i++)
            af[i] = *(const short8*)(&As[cb + (wm + i * 16 + l16) * 32 + rdoff]);
        #pragma unroll
        for (int j = 0; j < 4; j++)
            bf[j] = *(const short8*)(&Bs[cb + (wn + j * 16 + l16) * 32 + rdoff]);
        #pragma unroll
        for (int i = 0; i < 4; i++)
            #pragma unroll
            for (int j = 0; j < 4; j++)
                acc[i][j] = __builtin_amdgcn_mfma_f32_16x16x32_bf16(af[i], bf[j], acc[i][j], 0, 0, 0);
        __syncthreads();
        cur ^= 1;
    }

    #pragma unroll
    for (int i = 0; i < 4; i++) {
        #pragma unroll
        for (int j = 0; j < 4; j++) {
            int col = n0 + wn + j * 16 + l16;
            float bsv = (MODE == 3 && NS == 2 && ksplit == 1) ? 0.f : bias[col];
            if (MODE == 4 || (MODE == 5 && zsel == 2)) {
                __hip_bfloat16* vt = (__hip_bfloat16*)((MODE == 5) ? Cv2 : Cv);
                int mb = m0 + wm + i * 16 + quad * 4;
                int b = mb >> 11, s0 = mb & (Ss - 1);
                int h = col >> 6, d = col & (DH - 1);
                short4v pk;
                #pragma unroll
                for (int r = 0; r < 4; r++) pk[r] = f2bf(acc[i][j][r] + bsv);
                *(short4v*)(vt + ((size_t)(b * Hh + h) * DH + d) * Ss + s0) = pk;
                continue;
            }
            #pragma unroll
            for (int r = 0; r < 4; r++) {
                int m = m0 + wm + i * 16 + quad * 4 + r;
                if (m >= Me) continue;
                float val = acc[i][j][r] + bsv;
                if (MODE == 0) {
                    ((__hip_bfloat16*)Cv)[(size_t)m * N + col] = __float2bfloat16(val);
                } else if (MODE == 5) {
                    __hip_bfloat16* co = (__hip_bfloat16*)((zsel == 0) ? Cv : Ck);
                    co[(size_t)m * N + col] = __float2bfloat16(val);
                } else if (MODE == 1) {
                    ((float*)Cv)[(size_t)m * N + col] = val + residual[(size_t)m * N + col];
                } else if (MODE == 2) {
                    // gelu: tanh(z) = 1 - 2/(e^{2z}+1); saturates correctly at +-inf.
                    float z = 0.7978845608028654f * (val + 0.044715f * val * val * val);
                    float eg = __expf(2.f * z);
                    float th = 1.f - __fdividef(2.f, eg + 1.f);
                    ((__hip_bfloat16*)Cv)[(size_t)(hbase + m) * N + col] =
                        __float2bfloat16(0.5f * val * (1.f + th));
                } else { // MODE 3
                    float* o3 = (float*)((NS == 2 && ksplit == 1) ? Cv2 : Cv);
                    o3[(size_t)(hbase + m) * N + col] = val;
                }
            }
        }
    }
}

// ---------------------------------------------------------------------------
// MFMA flash attention, LDS-staged K/V. Block = 4 waves covering 64 queries.
// + T5 setprio around MFMA clusters (round-13 verified, +4us).
// Grid = (h, tile, b) so all tiles of one (b,h) map to one XCD: K/V L2-local.
__global__ __launch_bounds__(256) void attn_mfma(const __hip_bfloat16* __restrict__ q,
                                                 const __hip_bfloat16* __restrict__ k,
                                                 const __hip_bfloat16* __restrict__ Vt,
                                                 __hip_bfloat16* __restrict__ out) {
    int h = blockIdx.x, tile = blockIdx.y, b = blockIdx.z;
    int wave = threadIdx.x >> 6, lane = threadIdx.x & 63;
    int quad = lane >> 4, l16 = lane & 15;
    int q0 = tile * 64 + wave * 16;
    int tb = b * Ss;

    __shared__ __hip_bfloat16 Ks[32 * 72];   // [key][0..63 data], padded stride
    __shared__ __hip_bfloat16 Vs[64 * 40];   // [d][0..31 data], padded stride

    const __hip_bfloat16* qp = q + (size_t)(tb + q0 + l16) * (Hh * DH) + h * DH + quad * 8;
    short8 qf0 = *(const short8*)(qp);
    short8 qf1 = *(const short8*)(qp + 32);

    float4v oc[4];
    #pragma unroll
    for (int i = 0; i < 4; i++) oc[i] = (float4v)0.f;
    float lsum = 0.f;

    const __hip_bfloat16* kbase = k + (size_t)tb * (Hh * DH) + h * DH;
    const __hip_bfloat16* vbase = Vt + ((size_t)(b * Hh + h) * DH) * Ss;
    int qglob = q0 + l16;
    int srcA = (quad & 1) * 32 + l16;
    int srcB = srcA + 16;
    int sel = quad >> 1;
    int nsteps = 2 * tile + 2;

    int krow = threadIdx.x >> 3, kg = threadIdx.x & 7;   // K stage: 32 rows x 8x16B
    int vd   = threadIdx.x >> 2, vg = threadIdx.x & 3;   // V stage: 64 rows x 4x16B

    short8 kv = *(const short8*)(kbase + (size_t)krow * (Hh * DH) + kg * 8);
    short8 vv = *(const short8*)(vbase + (size_t)vd * Ss + vg * 8);

    for (int st = 0; st < nsteps; st++) {
        int k0 = st * 32;
        *(short8*)(&Ks[krow * 72 + kg * 8]) = kv;
        *(short8*)(&Vs[vd * 40 + vg * 8]) = vv;
        __syncthreads();
        if (st + 1 < nsteps) {
            kv = *(const short8*)(kbase + (size_t)(k0 + 32 + krow) * (Hh * DH) + kg * 8);
            vv = *(const short8*)(vbase + (size_t)vd * Ss + (k0 + 32) + vg * 8);
        }

        short8 a0 = *(const short8*)(&Ks[l16 * 72 + quad * 8]);
        short8 a1 = *(const short8*)(&Ks[l16 * 72 + 32 + quad * 8]);
        short8 a2 = *(const short8*)(&Ks[(l16 + 16) * 72 + quad * 8]);
        short8 a3 = *(const short8*)(&Ks[(l16 + 16) * 72 + 32 + quad * 8]);

        float4v c0 = (float4v)0.f, c1 = (float4v)0.f;
        __builtin_amdgcn_s_setprio(1);
        c0 = __builtin_amdgcn_mfma_f32_16x16x32_bf16(a0, qf0, c0, 0, 0, 0);
        c0 = __builtin_amdgcn_mfma_f32_16x16x32_bf16(a1, qf1, c0, 0, 0, 0);
        c1 = __builtin_amdgcn_mfma_f32_16x16x32_bf16(a2, qf0, c1, 0, 0, 0);
        c1 = __builtin_amdgcn_mfma_f32_16x16x32_bf16(a3, qf1, c1, 0, 0, 0);
        __builtin_amdgcn_s_setprio(0);

        float p0[4], p1[4];
        #pragma unroll
        for (int r = 0; r < 4; r++) {
            int key0 = k0 + quad * 4 + r;
            int key1 = key0 + 16;
            p0[r] = (key0 <= qglob) ? __expf(c0[r] * 0.125f - 4.f) : 0.f;
            p1[r] = (key1 <= qglob) ? __expf(c1[r] * 0.125f - 4.f) : 0.f;
            lsum += p0[r] + p1[r];
        }

        short8 pf;
        #pragma unroll
        for (int r = 0; r < 4; r++) {
            float t0 = __shfl(p0[r], srcA), t1 = __shfl(p1[r], srcA);
            pf[r] = f2bf(sel ? t1 : t0);
            float u0 = __shfl(p0[r], srcB), u1 = __shfl(p1[r], srcB);
            pf[4 + r] = f2bf(sel ? u1 : u0);
        }

        __builtin_amdgcn_s_setprio(1);
        #pragma unroll
        for (int nt = 0; nt < 4; nt++) {
            short8 bv = *(const short8*)(&Vs[(nt * 16 + l16) * 40 + quad * 8]);
            oc[nt] = __builtin_amdgcn_mfma_f32_16x16x32_bf16(pf, bv, oc[nt], 0, 0, 0);
        }
        __builtin_amdgcn_s_setprio(0);
        __syncthreads();
    }

    lsum += __shfl_xor(lsum, 16);
    lsum += __shfl_xor(lsum, 32);
    float linv[4];
    #pragma unroll
    for (int r = 0; r < 4; r++) linv[r] = 1.f / __shfl(lsum, quad * 4 + r);

    #pragma unroll
    for (int nt = 0; nt < 4; nt++) {
        #pragma unroll
        for (int r = 0; r < 4; r++) {
            int tokq = tb + q0 + quad * 4 + r;
            out[(size_t)tokq * (Hh * DH) + h * DH + nt * 16 + l16] =
                __float2bfloat16(oc[nt][r] * linv[r]);
        }
    }
}

// ---------------------------------------------------------------------------
// Gate: inline fp32 LN2 + softmax + top-2, block-aggregated atomics.
// Also WRITES ffn_in = bf16(LN2(working)) -- replaces the separate ln_kernel
// pass (the xn values are already computed here; only the mu/var reduction
// order differs from the old tree reduction, a sub-ULP fp32 difference).
#define GT 64   // tokens per block
__global__ __launch_bounds__(256) void gate_kernel(const float* __restrict__ wk,
                                                   const float* __restrict__ g2s,
                                                   const float* __restrict__ g2b,
                                                   const float* __restrict__ Wg,
                                                   const float* __restrict__ bg,
                                                   __hip_bfloat16* __restrict__ ffn,
                                                   float* __restrict__ psum,
                                                   int* __restrict__ counts,
                                                   int* __restrict__ bucket,
                                                   int* __restrict__ eidx,
                                                   int* __restrict__ epos,
                                                   float* __restrict__ ew) {
    int t0 = blockIdx.x * GT;
    int wave = threadIdx.x >> 6, lane = threadIdx.x & 63;

    __shared__ float sp[GT][Ee];
    __shared__ int   sel_e[2][GT];
    __shared__ int   spos[2][GT];
    __shared__ int   lbase[Ee];

    for (int i = wave; i < GT; i += 4) {
        int t = t0 + i;
        const float* xr = wk + (size_t)t * Dd;
        __hip_bfloat16* yr = ffn + (size_t)t * Dd;
        float xv[16];
        float s1 = 0.f, sq = 0.f;
        #pragma unroll
        for (int j = 0; j < 16; j++) {
            float v = xr[lane + j * 64];
            xv[j] = v; s1 += v; sq += v * v;
        }
        #pragma unroll
        for (int off = 32; off; off >>= 1) { s1 += __shfl_xor(s1, off); sq += __shfl_xor(sq, off); }
        float mu = s1 * (1.f / Dd), var = sq * (1.f / Dd) - mu * mu;
        float rstd = rsqrtf(var + 1e-6f);
        float acc[Ee] = {};
        #pragma unroll
        for (int j = 0; j < 16; j++) {
            int d = lane + j * 64;
            float xn = (xv[j] - mu) * rstd * g2s[d] + g2b[d];
            yr[d] = __float2bfloat16(xn);            // fused ffn_in write
            const float* wr = Wg + d * Ee;
            #pragma unroll
            for (int e = 0; e < Ee; e++) acc[e] += xn * wr[e];
        }
        #pragma unroll
        for (int e = 0; e < Ee; e++)
            #pragma unroll
            for (int off = 32; off; off >>= 1) acc[e] += __shfl_xor(acc[e], off);
        if (lane == 0) {
            float lg[Ee], mx = -1e30f;
            #pragma unroll
            for (int e = 0; e < Ee; e++) { lg[e] = acc[e] + bg[e]; mx = fmaxf(mx, lg[e]); }
            float p[Ee], ssum = 0.f;
            #pragma unroll
            for (int e = 0; e < Ee; e++) { p[e] = __expf(lg[e] - mx); ssum += p[e]; }
            float ise = 1.f / ssum;
            #pragma unroll
            for (int e = 0; e < Ee; e++) { p[e] *= ise; sp[i][e] = p[e]; }
            int e1 = 0;
            for (int e = 1; e < Ee; e++) if (p[e] > p[e1]) e1 = e;
            int e2 = -1;
            for (int e = 0; e < Ee; e++) if (e != e1 && (e2 < 0 || p[e] > p[e2])) e2 = e;
            sel_e[0][i] = e1; sel_e[1][i] = e2;
            float w1 = p[e1], w2 = p[e2], isw = 1.f / (w1 + w2);
            eidx[2 * t] = e1; ew[2 * t] = w1 * isw;
            eidx[2 * t + 1] = e2; ew[2 * t + 1] = w2 * isw;
        }
    }
    __syncthreads();

    if (threadIdx.x < Ee) {
        int e = threadIdx.x;
        int local = 0;
        for (int i = 0; i < GT; i++) {
            if (sel_e[0][i] == e) spos[0][i] = local++;
            if (sel_e[1][i] == e) spos[1][i] = local++;
        }
        lbase[e] = atomicAdd(&counts[e], local);
        float ps = 0.f;
        for (int i = 0; i < GT; i++) ps += sp[i][e];
        atomicAdd(&psum[e], ps);
    }
    __syncthreads();

    if (threadIdx.x < GT) {
        int i = threadIdx.x, t = t0 + i;
        #pragma unroll
        for (int s = 0; s < 2; s++) {
            int e = sel_e[s][i];
            int pos = lbase[e] + spos[s][i];
            bucket[e * Tt + pos] = t;
            epos[2 * t + s] = pos;
        }
    }
}

__global__ void zero_init(float* psum, int* counts) {
    int i = threadIdx.x;
    if (i < Ee) { psum[i] = 0.f; counts[i] = 0; }
}

__global__ void prefix_kernel(const int* counts, int* bases) {
    if (threadIdx.x == 0) {
        int run = 0;
        for (int e = 0; e < Ee; e++) { bases[e] = run; run += counts[e]; }
    }
}

// out[t] = working[t] + w0*(P0[slot0]{+P1[slot0]}) + w1*(P0[slot1]{+P1[slot1]})
__global__ __launch_bounds__(256) void combine_out(const float* __restrict__ working,
                                                   const float* __restrict__ O2,
                                                   const float* __restrict__ O2b,
                                                   const int* __restrict__ bases,
                                                   const int* __restrict__ eidx,
                                                   const int* __restrict__ epos,
                                                   const float* __restrict__ ew,
                                                   float* __restrict__ out,
                                                   int ns) {
    int t = blockIdx.x, tid = threadIdx.x;
    int e0 = eidx[2 * t], e1 = eidx[2 * t + 1];
    size_t r0 = (size_t)(bases[e0] + epos[2 * t]) * Dd;
    size_t r1 = (size_t)(bases[e1] + epos[2 * t + 1]) * Dd;
    float w0 = ew[2 * t], w1 = ew[2 * t + 1];
    const float4* wr = (const float4*)(working + (size_t)t * Dd);
    const float4* o0 = (const float4*)(O2 + r0);
    const float4* o1 = (const float4*)(O2 + r1);
    float4 a = wr[tid], x0 = o0[tid], x1 = o1[tid];
    if (ns == 2) {
        const float4* p0 = (const float4*)(O2b + r0);
        const float4* p1 = (const float4*)(O2b + r1);
        float4 y0 = p0[tid], y1 = p1[tid];
        x0.x += y0.x; x0.y += y0.y; x0.z += y0.z; x0.w += y0.w;
        x1.x += y1.x; x1.y += y1.y; x1.z += y1.z; x1.w += y1.w;
    }
    float4* dst = (float4*)(out + (size_t)t * Dd);
    dst[tid] = make_float4(a.x + w0 * x0.x + w1 * x1.x,
                           a.y + w0 * x0.y + w1 * x1.y,
                           a.z + w0 * x0.z + w1 * x1.z,
                           a.w + w0 * x0.w + w1 * x1.w);
}

__global__ void aux_kernel(const int* counts, const float* psum, float* out) {
    if (threadIdx.x == 0 && blockIdx.x == 0) {
        float a = 0.f;
        for (int e = 0; e < Ee; e++)
            a += (counts[e] * (1.f / Tt)) * (psum[e] * (1.f / Tt));
        out[0] = 0.01f * (float)Ee * a;
    }
}

// ---------------------------------------------------------------------------
extern "C" void kernel_launch(void* const* d_in, const int* in_sizes, int n_in,
                              void* d_out, int out_size, void* d_ws, size_t ws_size,
                              hipStream_t stream) {
    const float* x     = (const float*)d_in[0];
    const float* ln1_s = (const float*)d_in[1];
    const float* ln1_b = (const float*)d_in[2];
    const float* Wq    = (const float*)d_in[3];
    const float* bq    = (const float*)d_in[4];
    const float* Wk    = (const float*)d_in[5];
    const float* bk    = (const float*)d_in[6];
    const float* Wv    = (const float*)d_in[7];
    const float* bv    = (const float*)d_in[8];
    const float* Wo    = (const float*)d_in[9];
    const float* bo    = (const float*)d_in[10];
    const float* ln2_s = (const float*)d_in[11];
    const float* ln2_b = (const float*)d_in[12];
    const float* Wg    = (const float*)d_in[13];
    const float* bg    = (const float*)d_in[14];
    const float* W1    = (const float*)d_in[15];
    const float* b1    = (const float*)d_in[16];
    const float* W2    = (const float*)d_in[17];
    const float* b2    = (const float*)d_in[18];

    const size_t MBy = 1u << 20;
    char* base = (char*)d_ws;
    __hip_bfloat16* attn_in = (__hip_bfloat16*)(base);             // 0-8   (also attn_out)
    __hip_bfloat16* qbf     = (__hip_bfloat16*)(base + 8 * MBy);   // 8-16
    __hip_bfloat16* kbf     = (__hip_bfloat16*)(base + 16 * MBy);  // 16-24
    __hip_bfloat16* Vt      = (__hip_bfloat16*)(base + 24 * MBy);  // 24-32
    float*          working = (float*)(base + 32 * MBy);           // 32-48
    __hip_bfloat16* ffn_in  = (__hip_bfloat16*)(base + 48 * MBy);  // 48-56
    __hip_bfloat16* Hbuf    = (__hip_bfloat16*)(base + 56 * MBy);  // 56-120 (8192x4096 bf16)
    float*          O2      = (float*)(base);                      // 0-32  (overlays dead attn bufs)
    __hip_bfloat16* WT      = (__hip_bfloat16*)(base + 120 * MBy); // 120-184 shared (W1T then W2T)
    __hip_bfloat16* WqT     = (__hip_bfloat16*)(base + 120 * MBy); // QKVO transposes (dead before WT)
    __hip_bfloat16* WkT     = (__hip_bfloat16*)(base + 122 * MBy);
    __hip_bfloat16* WvT     = (__hip_bfloat16*)(base + 124 * MBy);
    __hip_bfloat16* WoT     = (__hip_bfloat16*)(base + 126 * MBy);
    char* rt = base + 184 * MBy;
    int*   bucket = (int*)rt;                        // 8*4096 ints
    int*   counts = (int*)(rt + Ee * Tt * 4);
    int*   bases  = counts + 64;
    float* psum   = (float*)(bases + 64);
    int*   eidx   = (int*)(psum + 64);               // 2*Tt
    int*   epos   = eidx + 2 * Tt;
    float* ew     = (float*)(epos + 2 * Tt);

    // split-K second partial buffer (only if workspace permits)
    bool   sk  = (ws_size >= (size_t)224 * MBy);
    float* O2b = sk ? (float*)(base + 192 * MBy) : O2;

    float* out  = (float*)d_out;
    float* auxp = out + (size_t)Tt * Dd;

    zero_init<<<1, 64, 0, stream>>>(psum, counts);
    transpose_qkvo<<<dim3(Dd / 64, Dd / 64, 4), 256, 0, stream>>>(
        Wq, Wk, Wv, Wo, WqT, WkT, WvT, WoT);
    ln_kernel<<<Tt, 256, 0, stream>>>(x, ln1_s, ln1_b, attn_in);

    dim3 gqkv(Dd / 128, Tt / 128);
    // fused QKV: z=0 -> qbf, z=1 -> kbf, z=2 -> Vt (transposed)
    gemm_mfma<5><<<dim3(Dd / 128, Tt / 128, 3), 256, 0, stream>>>(
        attn_in, WqT, bq, qbf, Tt, Dd, Dd,
        nullptr, nullptr, nullptr, nullptr, bk, bv, kbf, Vt);

    attn_mfma<<<dim3(Hh, Ss / 64, Bb), 256, 0, stream>>>(qbf, kbf, Vt, attn_in);

    gemm_mfma<1><<<gqkv, 256, 0, stream>>>(attn_in, WoT, bo, working, Tt, Dd, Dd,
                                           nullptr, nullptr, nullptr, x,
                                           nullptr, nullptr, nullptr, nullptr);

    // gate computes LN2 inline and writes ffn_in (replaces second ln_kernel)
    gate_kernel<<<Tt / GT, 256, 0, stream>>>(working, ln2_s, ln2_b, Wg, bg, ffn_in,
                                             psum, counts, bucket, eidx, epos, ew);
    prefix_kernel<<<1, 64, 0, stream>>>(counts, bases);

    transpose_we<<<dim3(FH / 64, Dd / 64, Ee), 256, 0, stream>>>(W1, WT, Dd, FH);
    gemm_mfma<2><<<dim3(FH / 128, Tt / 128, Ee), 256, 0, stream>>>(
        ffn_in, WT, b1, Hbuf, Tt, FH, Dd, bucket, counts, bases, nullptr,
        nullptr, nullptr, nullptr, nullptr);
    transpose_we<<<dim3(Dd / 64, FH / 64, Ee), 256, 0, stream>>>(W2, WT, FH, Dd);
    if (sk) {
        gemm_mfma<3, 2><<<dim3(Dd / 128, Tt / 128, 2 * Ee), 256, 0, stream>>>(
            Hbuf, WT, b2, O2, Tt, Dd, FH, bucket, counts, bases, nullptr,
            nullptr, nullptr, nullptr, O2b);
    } else {
        gemm_mfma<3, 1><<<dim3(Dd / 128, Tt / 128, Ee), 256, 0, stream>>>(
            Hbuf, WT, b2, O2, Tt, Dd, FH, bucket, counts, bases, nullptr,
            nullptr, nullptr, nullptr, nullptr);
    }

    combine_out<<<Tt, 256, 0, stream>>>(working, O2, O2b, bases, eidx, epos, ew, out,
                                        sk ? 2 : 1);
    aux_kernel<<<1, 64, 0, stream>>>(counts, psum, auxp);
}

// Round 15
// 834.343 us; speedup vs baseline: 1.0124x; 1.0124x over previous
//
#include <hip/hip_runtime.h>
#include <hip/hip_bf16.h>
#include <math.h>

#define Bb 2
#define Ss 2048
#define Dd 1024
#define Hh 16
#define DH 64
#define Ee 8
#define FH 4096
#define Tt (Bb*Ss)

typedef __attribute__((ext_vector_type(8))) short short8;
typedef __attribute__((ext_vector_type(4))) short short4v;
typedef __attribute__((ext_vector_type(4))) float float4v;

static __device__ inline short f2bf(float f) {
    __hip_bfloat16 h = __float2bfloat16(f);
    return *reinterpret_cast<short*>(&h);
}

// async global->LDS, 16B per lane. LDS dest = wave-uniform base + lane*16.
static __device__ inline void glds16(const __hip_bfloat16* g, __hip_bfloat16* l) {
    __builtin_amdgcn_global_load_lds(
        (const __attribute__((address_space(1))) unsigned int*)g,
        (__attribute__((address_space(3))) unsigned int*)l, 16, 0, 0);
}

// ---------------------------------------------------------------------------
// LayerNorm -> bf16. One block (256 thr) per token. (LN1 only; LN2 is fused
// into gate_kernel.)
__global__ __launch_bounds__(256) void ln_kernel(const float* __restrict__ x,
                                                 const float* __restrict__ sc,
                                                 const float* __restrict__ bi,
                                                 __hip_bfloat16* __restrict__ y) {
    int t = blockIdx.x, tid = threadIdx.x;
    const float* xr = x + (size_t)t * Dd;
    float s1 = 0.f, s2 = 0.f;
    for (int d = tid; d < Dd; d += 256) { float v = xr[d]; s1 += v; s2 += v * v; }
    __shared__ float r1[256], r2[256];
    r1[tid] = s1; r2[tid] = s2; __syncthreads();
    for (int off = 128; off > 0; off >>= 1) {
        if (tid < off) { r1[tid] += r1[tid + off]; r2[tid] += r2[tid + off]; }
        __syncthreads();
    }
    float mu = r1[0] * (1.f / Dd);
    float var = r2[0] * (1.f / Dd) - mu * mu;
    float rstd = rsqrtf(var + 1e-6f);
    __hip_bfloat16* yr = y + (size_t)t * Dd;
    for (int d = tid; d < Dd; d += 256) {
        float v = xr[d];
        yr[d] = __float2bfloat16((v - mu) * rstd * sc[d] + bi[d]);
    }
}

// ---------------------------------------------------------------------------
// Vectorized transpose+convert fp32 [K][N] -> bf16 [N][K]. 64x64 tiles:
// float4 global reads, short4v 8B writes, LDS [64][65] fp32 (pad 65).
__global__ __launch_bounds__(256) void transpose_qkvo(
    const float* W0, const float* W1, const float* W2, const float* W3,
    __hip_bfloat16* T0, __hip_bfloat16* T1, __hip_bfloat16* T2, __hip_bfloat16* T3) {
    int z = blockIdx.z;
    const float* W = (z == 0) ? W0 : (z == 1) ? W1 : (z == 2) ? W2 : W3;
    __hip_bfloat16* Wt = (z == 0) ? T0 : (z == 1) ? T1 : (z == 2) ? T2 : T3;
    __shared__ float tile[64][65];
    int k0 = blockIdx.y * 64, n0 = blockIdx.x * 64;
    int tx = threadIdx.x & 15, ty = threadIdx.x >> 4;
    #pragma unroll
    for (int p = 0; p < 4; p++) {
        float4 v = *(const float4*)(&W[(size_t)(k0 + ty + p * 16) * Dd + n0 + tx * 4]);
        tile[ty + p * 16][tx * 4 + 0] = v.x;
        tile[ty + p * 16][tx * 4 + 1] = v.y;
        tile[ty + p * 16][tx * 4 + 2] = v.z;
        tile[ty + p * 16][tx * 4 + 3] = v.w;
    }
    __syncthreads();
    #pragma unroll
    for (int p = 0; p < 4; p++) {
        int n = ty + p * 16;
        short4v pk;
        pk[0] = f2bf(tile[tx * 4 + 0][n]);
        pk[1] = f2bf(tile[tx * 4 + 1][n]);
        pk[2] = f2bf(tile[tx * 4 + 2][n]);
        pk[3] = f2bf(tile[tx * 4 + 3][n]);
        *(short4v*)(&Wt[(size_t)(n0 + n) * Dd + k0 + tx * 4]) = pk;
    }
}

// Batched expert-weight transpose (vectorized): W[e] fp32 [K][N] -> bf16 [N][K].
__global__ __launch_bounds__(256) void transpose_we(const float* __restrict__ W,
                                                    __hip_bfloat16* __restrict__ Wt,
                                                    int Kd, int N) {
    int e = blockIdx.z;
    W  += (size_t)e * Kd * N;
    Wt += (size_t)e * Kd * N;
    __shared__ float tile[64][65];
    int k0 = blockIdx.y * 64, n0 = blockIdx.x * 64;
    int tx = threadIdx.x & 15, ty = threadIdx.x >> 4;
    #pragma unroll
    for (int p = 0; p < 4; p++) {
        float4 v = *(const float4*)(&W[(size_t)(k0 + ty + p * 16) * N + n0 + tx * 4]);
        tile[ty + p * 16][tx * 4 + 0] = v.x;
        tile[ty + p * 16][tx * 4 + 1] = v.y;
        tile[ty + p * 16][tx * 4 + 2] = v.z;
        tile[ty + p * 16][tx * 4 + 3] = v.w;
    }
    __syncthreads();
    #pragma unroll
    for (int p = 0; p < 4; p++) {
        int n = ty + p * 16;
        short4v pk;
        pk[0] = f2bf(tile[tx * 4 + 0][n]);
        pk[1] = f2bf(tile[tx * 4 + 1][n]);
        pk[2] = f2bf(tile[tx * 4 + 2][n]);
        pk[3] = f2bf(tile[tx * 4 + 3][n]);
        *(short4v*)(&Wt[(size_t)(n0 + n) * Kd + k0 + tx * 4]) = pk;
    }
}

// ---------------------------------------------------------------------------
// bf16 MFMA GEMM, tile 128x128, BK=32, double-buffered global_load_lds staging
// (round-6 verified loop; launch-bounds (256,4) experiment REGRESSED MODE 2
// 148->163us via longer address code + L2 pressure -> reverted to plain 256,
// the verified 72-VGPR/3-wave allocation).
// LDS LINEAR [128][32]/buffer; both-sides slot swizzle:
// LDS (row, s) holds global 16B-slot s ^ ((row>>1)&3).
// MODE 0: plain -> bf16 C
// MODE 1: + residual fp32 -> fp32 C  (Wo)
// MODE 2: expert GEMM1: gather A rows via bucket, gelu -> Hbuf[base[e]+m] bf16
// MODE 3: expert GEMM2: A = H + base[e], fp32 out. NS=2: z=2e+s, split-K
//         halves; s=0 -> Cv (+bias), s=1 -> Cv2 (no bias). combine_out sums.
// MODE 4: V projection -> Vt[b][h][d][s] bf16 (transposed write)
// MODE 5: fused QKV: z in {0,1,2}; Bt += z*D*D; bias={bias,bias_k,bias_v}[z];
//         out: z=0->Cv(bf16), z=1->Ck(bf16), z=2->Cv2 (Vt transposed write).
template<int MODE, int NS = 1>
__global__ __launch_bounds__(256) void gemm_mfma(
    const __hip_bfloat16* __restrict__ A, const __hip_bfloat16* __restrict__ Bt,
    const float* __restrict__ bias, void* __restrict__ Cv,
    int M, int N, int Kd,
    const int* __restrict__ bucket, const int* __restrict__ cnts,
    const int* __restrict__ bases, const float* __restrict__ residual,
    const float* __restrict__ bias_k, const float* __restrict__ bias_v,
    void* __restrict__ Ck, void* __restrict__ Cv2)
{
    int Me = M;
    const int* rowIdx = nullptr;
    int hbase = 0;
    int ksplit = 0;
    int zsel = 0;
    if (MODE == 2 || MODE == 3) {
        int e = (NS == 2) ? (blockIdx.z >> 1) : blockIdx.z;
        if (NS == 2) ksplit = blockIdx.z & 1;
        Me = cnts[e];
        hbase = bases[e];
        Bt += (size_t)e * N * Kd;
        bias += (size_t)e * N;
        if (MODE == 2) rowIdx = bucket + e * Tt;
        if (MODE == 3) A += (size_t)hbase * Kd;
    }
    if (MODE == 5) {
        zsel = blockIdx.z;
        Bt += (size_t)zsel * Dd * Dd;
        if (zsel == 1) bias = bias_k;
        if (zsel == 2) bias = bias_v;
    }
    int m0 = blockIdx.y * 128;
    if (m0 >= Me) return;
    int n0 = blockIdx.x * 128;

    __shared__ __hip_bfloat16 As[2 * 128 * 32];
    __shared__ __hip_bfloat16 Bs[2 * 128 * 32];

    int tid = threadIdx.x;
    int lane = tid & 63, wave = tid >> 6;
    int wm = (wave & 1) * 64, wn = (wave >> 1) * 64;
    int quad = lane >> 4, l16 = lane & 15;

    int rs = lane >> 2;
    int sslot = (lane & 3) ^ ((lane >> 3) & 3);
    int rowS0 = 16 * (2 * wave + 0) + rs;
    int rowS1 = 16 * (2 * wave + 1) + rs;

    const __hip_bfloat16 *gA0, *gA1;
    if (MODE == 2) {
        int g0 = m0 + rowS0, g1 = m0 + rowS1;
        int r0 = (g0 < Me) ? rowIdx[g0] : 0;
        int r1 = (g1 < Me) ? rowIdx[g1] : 0;
        gA0 = A + (size_t)r0 * Kd + sslot * 8;
        gA1 = A + (size_t)r1 * Kd + sslot * 8;
    } else {
        gA0 = A + (size_t)(m0 + rowS0) * Kd + sslot * 8;
        gA1 = A + (size_t)(m0 + rowS1) * Kd + sslot * 8;
    }
    const __hip_bfloat16* gB0 = Bt + (size_t)(n0 + rowS0) * Kd + sslot * 8;
    const __hip_bfloat16* gB1 = Bt + (size_t)(n0 + rowS1) * Kd + sslot * 8;

    __hip_bfloat16* lA0 = As + (2 * wave + 0) * 512;
    __hip_bfloat16* lA1 = As + (2 * wave + 1) * 512;
    __hip_bfloat16* lB0 = Bs + (2 * wave + 0) * 512;
    __hip_bfloat16* lB1 = Bs + (2 * wave + 1) * 512;

    int rsw = (l16 >> 1) & 3;
    int rdoff = (quad ^ rsw) * 8;

    float4v acc[4][4];
    #pragma unroll
    for (int i = 0; i < 4; i++)
        #pragma unroll
        for (int j = 0; j < 4; j++) acc[i][j] = (float4v)0.f;

    const int NT = Kd >> 5;
    int t0s = 0, t1s = NT;
    if (NS == 2) { int hlf = NT >> 1; t0s = ksplit * hlf; t1s = t0s + hlf; }

    {
        int ko = t0s << 5;
        glds16(gA0 + ko, lA0);
        glds16(gA1 + ko, lA1);
        glds16(gB0 + ko, lB0);
        glds16(gB1 + ko, lB1);
    }
    __syncthreads();

    int cur = 0;
    for (int t = t0s; t < t1s; t++) {
        if (t + 1 < t1s) {
            int ko = (t + 1) << 5;
            int bo = (cur ^ 1) * 4096;
            glds16(gA0 + ko, lA0 + bo);
            glds16(gA1 + ko, lA1 + bo);
            glds16(gB0 + ko, lB0 + bo);
            glds16(gB1 + ko, lB1 + bo);
        }
        int cb = cur * 4096;
        short8 af[4], bf[4];
        #pragma unroll
        for (int i = 0; i < 4; i++)
            af[i] = *(const short8*)(&As[cb + (wm + i * 16 + l16) * 32 + rdoff]);
        #pragma unroll
        for (int j = 0; j < 4; j++)
            bf[j] = *(const short8*)(&Bs[cb + (wn + j * 16 + l16) * 32 + rdoff]);
        #pragma unroll
        for (int i = 0; i < 4; i++)
            #pragma unroll
            for (int j = 0; j < 4; j++)
                acc[i][j] = __builtin_amdgcn_mfma_f32_16x16x32_bf16(af[i], bf[j], acc[i][j], 0, 0, 0);
        __syncthreads();
        cur ^= 1;
    }

    #pragma unroll
    for (int i = 0; i < 4; i++) {
        #pragma unroll
        for (int j = 0; j < 4; j++) {
            int col = n0 + wn + j * 16 + l16;
            float bsv = (MODE == 3 && NS == 2 && ksplit == 1) ? 0.f : bias[col];
            if (MODE == 4 || (MODE == 5 && zsel == 2)) {
                __hip_bfloat16* vt = (__hip_bfloat16*)((MODE == 5) ? Cv2 : Cv);
                int mb = m0 + wm + i * 16 + quad * 4;
                int b = mb >> 11, s0 = mb & (Ss - 1);
                int h = col >> 6, d = col & (DH - 1);
                short4v pk;
                #pragma unroll
                for (int r = 0; r < 4; r++) pk[r] = f2bf(acc[i][j][r] + bsv);
                *(short4v*)(vt + ((size_t)(b * Hh + h) * DH + d) * Ss + s0) = pk;
                continue;
            }
            #pragma unroll
            for (int r = 0; r < 4; r++) {
                int m = m0 + wm + i * 16 + quad * 4 + r;
                if (m >= Me) continue;
                float val = acc[i][j][r] + bsv;
                if (MODE == 0) {
                    ((__hip_bfloat16*)Cv)[(size_t)m * N + col] = __float2bfloat16(val);
                } else if (MODE == 5) {
                    __hip_bfloat16* co = (__hip_bfloat16*)((zsel == 0) ? Cv : Ck);
                    co[(size_t)m * N + col] = __float2bfloat16(val);
                } else if (MODE == 1) {
                    ((float*)Cv)[(size_t)m * N + col] = val + residual[(size_t)m * N + col];
                } else if (MODE == 2) {
                    // gelu: tanh(z) = 1 - 2/(e^{2z}+1); saturates correctly at +-inf.
                    float z = 0.7978845608028654f * (val + 0.044715f * val * val * val);
                    float eg = __expf(2.f * z);
                    float th = 1.f - __fdividef(2.f, eg + 1.f);
                    ((__hip_bfloat16*)Cv)[(size_t)(hbase + m) * N + col] =
                        __float2bfloat16(0.5f * val * (1.f + th));
                } else { // MODE 3
                    float* o3 = (float*)((NS == 2 && ksplit == 1) ? Cv2 : Cv);
                    o3[(size_t)(hbase + m) * N + col] = val;
                }
            }
        }
    }
}

// ---------------------------------------------------------------------------
// MFMA flash attention, LDS-staged K/V. Block = 4 waves covering 64 queries.
// + T5 setprio around MFMA clusters (round-13 verified, +4us).
// Grid = (h, tile, b) so all tiles of one (b,h) map to one XCD: K/V L2-local.
__global__ __launch_bounds__(256) void attn_mfma(const __hip_bfloat16* __restrict__ q,
                                                 const __hip_bfloat16* __restrict__ k,
                                                 const __hip_bfloat16* __restrict__ Vt,
                                                 __hip_bfloat16* __restrict__ out) {
    int h = blockIdx.x, tile = blockIdx.y, b = blockIdx.z;
    int wave = threadIdx.x >> 6, lane = threadIdx.x & 63;
    int quad = lane >> 4, l16 = lane & 15;
    int q0 = tile * 64 + wave * 16;
    int tb = b * Ss;

    __shared__ __hip_bfloat16 Ks[32 * 72];   // [key][0..63 data], padded stride
    __shared__ __hip_bfloat16 Vs[64 * 40];   // [d][0..31 data], padded stride

    const __hip_bfloat16* qp = q + (size_t)(tb + q0 + l16) * (Hh * DH) + h * DH + quad * 8;
    short8 qf0 = *(const short8*)(qp);
    short8 qf1 = *(const short8*)(qp + 32);

    float4v oc[4];
    #pragma unroll
    for (int i = 0; i < 4; i++) oc[i] = (float4v)0.f;
    float lsum = 0.f;

    const __hip_bfloat16* kbase = k + (size_t)tb * (Hh * DH) + h * DH;
    const __hip_bfloat16* vbase = Vt + ((size_t)(b * Hh + h) * DH) * Ss;
    int qglob = q0 + l16;
    int srcA = (quad & 1) * 32 + l16;
    int srcB = srcA + 16;
    int sel = quad >> 1;
    int nsteps = 2 * tile + 2;

    int krow = threadIdx.x >> 3, kg = threadIdx.x & 7;   // K stage: 32 rows x 8x16B
    int vd   = threadIdx.x >> 2, vg = threadIdx.x & 3;   // V stage: 64 rows x 4x16B

    short8 kv = *(const short8*)(kbase + (size_t)krow * (Hh * DH) + kg * 8);
    short8 vv = *(const short8*)(vbase + (size_t)vd * Ss + vg * 8);

    for (int st = 0; st < nsteps; st++) {
        int k0 = st * 32;
        *(short8*)(&Ks[krow * 72 + kg * 8]) = kv;
        *(short8*)(&Vs[vd * 40 + vg * 8]) = vv;
        __syncthreads();
        if (st + 1 < nsteps) {
            kv = *(const short8*)(kbase + (size_t)(k0 + 32 + krow) * (Hh * DH) + kg * 8);
            vv = *(const short8*)(vbase + (size_t)vd * Ss + (k0 + 32) + vg * 8);
        }

        short8 a0 = *(const short8*)(&Ks[l16 * 72 + quad * 8]);
        short8 a1 = *(const short8*)(&Ks[l16 * 72 + 32 + quad * 8]);
        short8 a2 = *(const short8*)(&Ks[(l16 + 16) * 72 + quad * 8]);
        short8 a3 = *(const short8*)(&Ks[(l16 + 16) * 72 + 32 + quad * 8]);

        float4v c0 = (float4v)0.f, c1 = (float4v)0.f;
        __builtin_amdgcn_s_setprio(1);
        c0 = __builtin_amdgcn_mfma_f32_16x16x32_bf16(a0, qf0, c0, 0, 0, 0);
        c0 = __builtin_amdgcn_mfma_f32_16x16x32_bf16(a1, qf1, c0, 0, 0, 0);
        c1 = __builtin_amdgcn_mfma_f32_16x16x32_bf16(a2, qf0, c1, 0, 0, 0);
        c1 = __builtin_amdgcn_mfma_f32_16x16x32_bf16(a3, qf1, c1, 0, 0, 0);
        __builtin_amdgcn_s_setprio(0);

        float p0[4], p1[4];
        #pragma unroll
        for (int r = 0; r < 4; r++) {
            int key0 = k0 + quad * 4 + r;
            int key1 = key0 + 16;
            p0[r] = (key0 <= qglob) ? __expf(c0[r] * 0.125f - 4.f) : 0.f;
            p1[r] = (key1 <= qglob) ? __expf(c1[r] * 0.125f - 4.f) : 0.f;
            lsum += p0[r] + p1[r];
        }

        short8 pf;
        #pragma unroll
        for (int r = 0; r < 4; r++) {
            float t0 = __shfl(p0[r], srcA), t1 = __shfl(p1[r], srcA);
            pf[r] = f2bf(sel ? t1 : t0);
            float u0 = __shfl(p0[r], srcB), u1 = __shfl(p1[r], srcB);
            pf[4 + r] = f2bf(sel ? u1 : u0);
        }

        __builtin_amdgcn_s_setprio(1);
        #pragma unroll
        for (int nt = 0; nt < 4; nt++) {
            short8 bv = *(const short8*)(&Vs[(nt * 16 + l16) * 40 + quad * 8]);
            oc[nt] = __builtin_amdgcn_mfma_f32_16x16x32_bf16(pf, bv, oc[nt], 0, 0, 0);
        }
        __builtin_amdgcn_s_setprio(0);
        __syncthreads();
    }

    lsum += __shfl_xor(lsum, 16);
    lsum += __shfl_xor(lsum, 32);
    float linv[4];
    #pragma unroll
    for (int r = 0; r < 4; r++) linv[r] = 1.f / __shfl(lsum, quad * 4 + r);

    #pragma unroll
    for (int nt = 0; nt < 4; nt++) {
        #pragma unroll
        for (int r = 0; r < 4; r++) {
            int tokq = tb + q0 + quad * 4 + r;
            out[(size_t)tokq * (Hh * DH) + h * DH + nt * 16 + l16] =
                __float2bfloat16(oc[nt][r] * linv[r]);
        }
    }
}

// ---------------------------------------------------------------------------
// Gate: inline fp32 LN2 + softmax + top-2, block-aggregated atomics.
// Also WRITES ffn_in = bf16(LN2(working)) -- replaces the separate ln_kernel
// pass (round-14 verified fusion; sub-ULP reduction-order difference only).
#define GT 64   // tokens per block
__global__ __launch_bounds__(256) void gate_kernel(const float* __restrict__ wk,
                                                   const float* __restrict__ g2s,
                                                   const float* __restrict__ g2b,
                                                   const float* __restrict__ Wg,
                                                   const float* __restrict__ bg,
                                                   __hip_bfloat16* __restrict__ ffn,
                                                   float* __restrict__ psum,
                                                   int* __restrict__ counts,
                                                   int* __restrict__ bucket,
                                                   int* __restrict__ eidx,
                                                   int* __restrict__ epos,
                                                   float* __restrict__ ew) {
    int t0 = blockIdx.x * GT;
    int wave = threadIdx.x >> 6, lane = threadIdx.x & 63;

    __shared__ float sp[GT][Ee];
    __shared__ int   sel_e[2][GT];
    __shared__ int   spos[2][GT];
    __shared__ int   lbase[Ee];

    for (int i = wave; i < GT; i += 4) {
        int t = t0 + i;
        const float* xr = wk + (size_t)t * Dd;
        __hip_bfloat16* yr = ffn + (size_t)t * Dd;
        float xv[16];
        float s1 = 0.f, sq = 0.f;
        #pragma unroll
        for (int j = 0; j < 16; j++) {
            float v = xr[lane + j * 64];
            xv[j] = v; s1 += v; sq += v * v;
        }
        #pragma unroll
        for (int off = 32; off; off >>= 1) { s1 += __shfl_xor(s1, off); sq += __shfl_xor(sq, off); }
        float mu = s1 * (1.f / Dd), var = sq * (1.f / Dd) - mu * mu;
        float rstd = rsqrtf(var + 1e-6f);
        float acc[Ee] = {};
        #pragma unroll
        for (int j = 0; j < 16; j++) {
            int d = lane + j * 64;
            float xn = (xv[j] - mu) * rstd * g2s[d] + g2b[d];
            yr[d] = __float2bfloat16(xn);            // fused ffn_in write
            const float* wr = Wg + d * Ee;
            #pragma unroll
            for (int e = 0; e < Ee; e++) acc[e] += xn * wr[e];
        }
        #pragma unroll
        for (int e = 0; e < Ee; e++)
            #pragma unroll
            for (int off = 32; off; off >>= 1) acc[e] += __shfl_xor(acc[e], off);
        if (lane == 0) {
            float lg[Ee], mx = -1e30f;
            #pragma unroll
            for (int e = 0; e < Ee; e++) { lg[e] = acc[e] + bg[e]; mx = fmaxf(mx, lg[e]); }
            float p[Ee], ssum = 0.f;
            #pragma unroll
            for (int e = 0; e < Ee; e++) { p[e] = __expf(lg[e] - mx); ssum += p[e]; }
            float ise = 1.f / ssum;
            #pragma unroll
            for (int e = 0; e < Ee; e++) { p[e] *= ise; sp[i][e] = p[e]; }
            int e1 = 0;
            for (int e = 1; e < Ee; e++) if (p[e] > p[e1]) e1 = e;
            int e2 = -1;
            for (int e = 0; e < Ee; e++) if (e != e1 && (e2 < 0 || p[e] > p[e2])) e2 = e;
            sel_e[0][i] = e1; sel_e[1][i] = e2;
            float w1 = p[e1], w2 = p[e2], isw = 1.f / (w1 + w2);
            eidx[2 * t] = e1; ew[2 * t] = w1 * isw;
            eidx[2 * t + 1] = e2; ew[2 * t + 1] = w2 * isw;
        }
    }
    __syncthreads();

    if (threadIdx.x < Ee) {
        int e = threadIdx.x;
        int local = 0;
        for (int i = 0; i < GT; i++) {
            if (sel_e[0][i] == e) spos[0][i] = local++;
            if (sel_e[1][i] == e) spos[1][i] = local++;
        }
        lbase[e] = atomicAdd(&counts[e], local);
        float ps = 0.f;
        for (int i = 0; i < GT; i++) ps += sp[i][e];
        atomicAdd(&psum[e], ps);
    }
    __syncthreads();

    if (threadIdx.x < GT) {
        int i = threadIdx.x, t = t0 + i;
        #pragma unroll
        for (int s = 0; s < 2; s++) {
            int e = sel_e[s][i];
            int pos = lbase[e] + spos[s][i];
            bucket[e * Tt + pos] = t;
            epos[2 * t + s] = pos;
        }
    }
}

__global__ void zero_init(float* psum, int* counts) {
    int i = threadIdx.x;
    if (i < Ee) { psum[i] = 0.f; counts[i] = 0; }
}

__global__ void prefix_kernel(const int* counts, int* bases) {
    if (threadIdx.x == 0) {
        int run = 0;
        for (int e = 0; e < Ee; e++) { bases[e] = run; run += counts[e]; }
    }
}

// out[t] = working[t] + w0*(P0[slot0]{+P1[slot0]}) + w1*(P0[slot1]{+P1[slot1]})
__global__ __launch_bounds__(256) void combine_out(const float* __restrict__ working,
                                                   const float* __restrict__ O2,
                                                   const float* __restrict__ O2b,
                                                   const int* __restrict__ bases,
                                                   const int* __restrict__ eidx,
                                                   const int* __restrict__ epos,
                                                   const float* __restrict__ ew,
                                                   float* __restrict__ out,
                                                   int ns) {
    int t = blockIdx.x, tid = threadIdx.x;
    int e0 = eidx[2 * t], e1 = eidx[2 * t + 1];
    size_t r0 = (size_t)(bases[e0] + epos[2 * t]) * Dd;
    size_t r1 = (size_t)(bases[e1] + epos[2 * t + 1]) * Dd;
    float w0 = ew[2 * t], w1 = ew[2 * t + 1];
    const float4* wr = (const float4*)(working + (size_t)t * Dd);
    const float4* o0 = (const float4*)(O2 + r0);
    const float4* o1 = (const float4*)(O2 + r1);
    float4 a = wr[tid], x0 = o0[tid], x1 = o1[tid];
    if (ns == 2) {
        const float4* p0 = (const float4*)(O2b + r0);
        const float4* p1 = (const float4*)(O2b + r1);
        float4 y0 = p0[tid], y1 = p1[tid];
        x0.x += y0.x; x0.y += y0.y; x0.z += y0.z; x0.w += y0.w;
        x1.x += y1.x; x1.y += y1.y; x1.z += y1.z; x1.w += y1.w;
    }
    float4* dst = (float4*)(out + (size_t)t * Dd);
    dst[tid] = make_float4(a.x + w0 * x0.x + w1 * x1.x,
                           a.y + w0 * x0.y + w1 * x1.y,
                           a.z + w0 * x0.z + w1 * x1.z,
                           a.w + w0 * x0.w + w1 * x1.w);
}

__global__ void aux_kernel(const int* counts, const float* psum, float* out) {
    if (threadIdx.x == 0 && blockIdx.x == 0) {
        float a = 0.f;
        for (int e = 0; e < Ee; e++)
            a += (counts[e] * (1.f / Tt)) * (psum[e] * (1.f / Tt));
        out[0] = 0.01f * (float)Ee * a;
    }
}

// ---------------------------------------------------------------------------
extern "C" void kernel_launch(void* const* d_in, const int* in_sizes, int n_in,
                              void* d_out, int out_size, void* d_ws, size_t ws_size,
                              hipStream_t stream) {
    const float* x     = (const float*)d_in[0];
    const float* ln1_s = (const float*)d_in[1];
    const float* ln1_b = (const float*)d_in[2];
    const float* Wq    = (const float*)d_in[3];
    const float* bq    = (const float*)d_in[4];
    const float* Wk    = (const float*)d_in[5];
    const float* bk    = (const float*)d_in[6];
    const float* Wv    = (const float*)d_in[7];
    const float* bv    = (const float*)d_in[8];
    const float* Wo    = (const float*)d_in[9];
    const float* bo    = (const float*)d_in[10];
    const float* ln2_s = (const float*)d_in[11];
    const float* ln2_b = (const float*)d_in[12];
    const float* Wg    = (const float*)d_in[13];
    const float* bg    = (const float*)d_in[14];
    const float* W1    = (const float*)d_in[15];
    const float* b1    = (const float*)d_in[16];
    const float* W2    = (const float*)d_in[17];
    const float* b2    = (const float*)d_in[18];

    const size_t MBy = 1u << 20;
    char* base = (char*)d_ws;
    __hip_bfloat16* attn_in = (__hip_bfloat16*)(base);             // 0-8   (also attn_out)
    __hip_bfloat16* qbf     = (__hip_bfloat16*)(base + 8 * MBy);   // 8-16
    __hip_bfloat16* kbf     = (__hip_bfloat16*)(base + 16 * MBy);  // 16-24
    __hip_bfloat16* Vt      = (__hip_bfloat16*)(base + 24 * MBy);  // 24-32
    float*          working = (float*)(base + 32 * MBy);           // 32-48
    __hip_bfloat16* ffn_in  = (__hip_bfloat16*)(base + 48 * MBy);  // 48-56
    __hip_bfloat16* Hbuf    = (__hip_bfloat16*)(base + 56 * MBy);  // 56-120 (8192x4096 bf16)
    float*          O2      = (float*)(base);                      // 0-32  (overlays dead attn bufs)
    __hip_bfloat16* WT      = (__hip_bfloat16*)(base + 120 * MBy); // 120-184 shared (W1T then W2T)
    __hip_bfloat16* WqT     = (__hip_bfloat16*)(base + 120 * MBy); // QKVO transposes (dead before WT)
    __hip_bfloat16* WkT     = (__hip_bfloat16*)(base + 122 * MBy);
    __hip_bfloat16* WvT     = (__hip_bfloat16*)(base + 124 * MBy);
    __hip_bfloat16* WoT     = (__hip_bfloat16*)(base + 126 * MBy);
    char* rt = base + 184 * MBy;
    int*   bucket = (int*)rt;                        // 8*4096 ints
    int*   counts = (int*)(rt + Ee * Tt * 4);
    int*   bases  = counts + 64;
    float* psum   = (float*)(bases + 64);
    int*   eidx   = (int*)(psum + 64);               // 2*Tt
    int*   epos   = eidx + 2 * Tt;
    float* ew     = (float*)(epos + 2 * Tt);

    // split-K second partial buffer (only if workspace permits)
    bool   sk  = (ws_size >= (size_t)224 * MBy);
    float* O2b = sk ? (float*)(base + 192 * MBy) : O2;

    float* out  = (float*)d_out;
    float* auxp = out + (size_t)Tt * Dd;

    zero_init<<<1, 64, 0, stream>>>(psum, counts);
    transpose_qkvo<<<dim3(Dd / 64, Dd / 64, 4), 256, 0, stream>>>(
        Wq, Wk, Wv, Wo, WqT, WkT, WvT, WoT);
    ln_kernel<<<Tt, 256, 0, stream>>>(x, ln1_s, ln1_b, attn_in);

    dim3 gqkv(Dd / 128, Tt / 128);
    // fused QKV: z=0 -> qbf, z=1 -> kbf, z=2 -> Vt (transposed)
    gemm_mfma<5><<<dim3(Dd / 128, Tt / 128, 3), 256, 0, stream>>>(
        attn_in, WqT, bq, qbf, Tt, Dd, Dd,
        nullptr, nullptr, nullptr, nullptr, bk, bv, kbf, Vt);

    attn_mfma<<<dim3(Hh, Ss / 64, Bb), 256, 0, stream>>>(qbf, kbf, Vt, attn_in);

    gemm_mfma<1><<<gqkv, 256, 0, stream>>>(attn_in, WoT, bo, working, Tt, Dd, Dd,
                                           nullptr, nullptr, nullptr, x,
                                           nullptr, nullptr, nullptr, nullptr);

    // gate computes LN2 inline and writes ffn_in (replaces second ln_kernel)
    gate_kernel<<<Tt / GT, 256, 0, stream>>>(working, ln2_s, ln2_b, Wg, bg, ffn_in,
                                             psum, counts, bucket, eidx, epos, ew);
    prefix_kernel<<<1, 64, 0, stream>>>(counts, bases);

    transpose_we<<<dim3(FH / 64, Dd / 64, Ee), 256, 0, stream>>>(W1, WT, Dd, FH);
    gemm_mfma<2><<<dim3(FH / 128, Tt / 128, Ee), 256, 0, stream>>>(
        ffn_in, WT, b1, Hbuf, Tt, FH, Dd, bucket, counts, bases, nullptr,
        nullptr, nullptr, nullptr, nullptr);
    transpose_we<<<dim3(Dd / 64, FH / 64, Ee), 256, 0, stream>>>(W2, WT, FH, Dd);
    if (sk) {
        gemm_mfma<3, 2><<<dim3(Dd / 128, Tt / 128, 2 * Ee), 256, 0, stream>>>(
            Hbuf, WT, b2, O2, Tt, Dd, FH, bucket, counts, bases, nullptr,
            nullptr, nullptr, nullptr, O2b);
    } else {
        gemm_mfma<3, 1><<<dim3(Dd / 128, Tt / 128, Ee), 256, 0, stream>>>(
            Hbuf, WT, b2, O2, Tt, Dd, FH, bucket, counts, bases, nullptr,
            nullptr, nullptr, nullptr, nullptr);
    }

    combine_out<<<Tt, 256, 0, stream>>>(working, O2, O2b, bases, eidx, epos, ew, out,
                                        sk ? 2 : 1);
    aux_kernel<<<1, 64, 0, stream>>>(counts, psum, auxp);
}

// Round 16
// 830.887 us; speedup vs baseline: 1.0166x; 1.0042x over previous
//
#include <hip/hip_runtime.h>
#include <hip/hip_bf16.h>
#include <math.h>

#define Bb 2
#define Ss 2048
#define Dd 1024
#define Hh 16
#define DH 64
#define Ee 8
#define FH 4096
#define Tt (Bb*Ss)

typedef __attribute__((ext_vector_type(8))) short short8;
typedef __attribute__((ext_vector_type(4))) short short4v;
typedef __attribute__((ext_vector_type(4))) float float4v;

static __device__ inline short f2bf(float f) {
    __hip_bfloat16 h = __float2bfloat16(f);
    return *reinterpret_cast<short*>(&h);
}

// async global->LDS, 16B per lane. LDS dest = wave-uniform base + lane*16.
static __device__ inline void glds16(const __hip_bfloat16* g, __hip_bfloat16* l) {
    __builtin_amdgcn_global_load_lds(
        (const __attribute__((address_space(1))) unsigned int*)g,
        (__attribute__((address_space(3))) unsigned int*)l, 16, 0, 0);
}

// ---------------------------------------------------------------------------
// LayerNorm -> bf16. One block (256 thr) per token. (LN1 only; LN2 is fused
// into gate_kernel.)
__global__ __launch_bounds__(256) void ln_kernel(const float* __restrict__ x,
                                                 const float* __restrict__ sc,
                                                 const float* __restrict__ bi,
                                                 __hip_bfloat16* __restrict__ y) {
    int t = blockIdx.x, tid = threadIdx.x;
    const float* xr = x + (size_t)t * Dd;
    float s1 = 0.f, s2 = 0.f;
    for (int d = tid; d < Dd; d += 256) { float v = xr[d]; s1 += v; s2 += v * v; }
    __shared__ float r1[256], r2[256];
    r1[tid] = s1; r2[tid] = s2; __syncthreads();
    for (int off = 128; off > 0; off >>= 1) {
        if (tid < off) { r1[tid] += r1[tid + off]; r2[tid] += r2[tid + off]; }
        __syncthreads();
    }
    float mu = r1[0] * (1.f / Dd);
    float var = r2[0] * (1.f / Dd) - mu * mu;
    float rstd = rsqrtf(var + 1e-6f);
    __hip_bfloat16* yr = y + (size_t)t * Dd;
    for (int d = tid; d < Dd; d += 256) {
        float v = xr[d];
        yr[d] = __float2bfloat16((v - mu) * rstd * sc[d] + bi[d]);
    }
}

// ---------------------------------------------------------------------------
// Vectorized transpose+convert fp32 [K][N] -> bf16 [N][K]. 64x64 tiles.
// Block (0,0,0) also zeroes psum/counts (replaces zero_init launch).
__global__ __launch_bounds__(256) void transpose_qkvo(
    const float* W0, const float* W1, const float* W2, const float* W3,
    __hip_bfloat16* T0, __hip_bfloat16* T1, __hip_bfloat16* T2, __hip_bfloat16* T3,
    float* __restrict__ psum, int* __restrict__ counts) {
    if (blockIdx.x == 0 && blockIdx.y == 0 && blockIdx.z == 0 && threadIdx.x < Ee) {
        psum[threadIdx.x] = 0.f;
        counts[threadIdx.x] = 0;
    }
    int z = blockIdx.z;
    const float* W = (z == 0) ? W0 : (z == 1) ? W1 : (z == 2) ? W2 : W3;
    __hip_bfloat16* Wt = (z == 0) ? T0 : (z == 1) ? T1 : (z == 2) ? T2 : T3;
    __shared__ float tile[64][65];
    int k0 = blockIdx.y * 64, n0 = blockIdx.x * 64;
    int tx = threadIdx.x & 15, ty = threadIdx.x >> 4;
    #pragma unroll
    for (int p = 0; p < 4; p++) {
        float4 v = *(const float4*)(&W[(size_t)(k0 + ty + p * 16) * Dd + n0 + tx * 4]);
        tile[ty + p * 16][tx * 4 + 0] = v.x;
        tile[ty + p * 16][tx * 4 + 1] = v.y;
        tile[ty + p * 16][tx * 4 + 2] = v.z;
        tile[ty + p * 16][tx * 4 + 3] = v.w;
    }
    __syncthreads();
    #pragma unroll
    for (int p = 0; p < 4; p++) {
        int n = ty + p * 16;
        short4v pk;
        pk[0] = f2bf(tile[tx * 4 + 0][n]);
        pk[1] = f2bf(tile[tx * 4 + 1][n]);
        pk[2] = f2bf(tile[tx * 4 + 2][n]);
        pk[3] = f2bf(tile[tx * 4 + 3][n]);
        *(short4v*)(&Wt[(size_t)(n0 + n) * Dd + k0 + tx * 4]) = pk;
    }
}

// Batched expert-weight transpose (vectorized): W[e] fp32 [K][N] -> bf16 [N][K].
__global__ __launch_bounds__(256) void transpose_we(const float* __restrict__ W,
                                                    __hip_bfloat16* __restrict__ Wt,
                                                    int Kd, int N) {
    int e = blockIdx.z;
    W  += (size_t)e * Kd * N;
    Wt += (size_t)e * Kd * N;
    __shared__ float tile[64][65];
    int k0 = blockIdx.y * 64, n0 = blockIdx.x * 64;
    int tx = threadIdx.x & 15, ty = threadIdx.x >> 4;
    #pragma unroll
    for (int p = 0; p < 4; p++) {
        float4 v = *(const float4*)(&W[(size_t)(k0 + ty + p * 16) * N + n0 + tx * 4]);
        tile[ty + p * 16][tx * 4 + 0] = v.x;
        tile[ty + p * 16][tx * 4 + 1] = v.y;
        tile[ty + p * 16][tx * 4 + 2] = v.z;
        tile[ty + p * 16][tx * 4 + 3] = v.w;
    }
    __syncthreads();
    #pragma unroll
    for (int p = 0; p < 4; p++) {
        int n = ty + p * 16;
        short4v pk;
        pk[0] = f2bf(tile[tx * 4 + 0][n]);
        pk[1] = f2bf(tile[tx * 4 + 1][n]);
        pk[2] = f2bf(tile[tx * 4 + 2][n]);
        pk[3] = f2bf(tile[tx * 4 + 3][n]);
        *(short4v*)(&Wt[(size_t)(n0 + n) * Kd + k0 + tx * 4]) = pk;
    }
}

// ---------------------------------------------------------------------------
// bf16 MFMA GEMM, tile 128x128, BK=32, double-buffered global_load_lds staging
// (round-6 verified loop). LDS LINEAR [128][32]/buffer; both-sides slot
// swizzle: LDS (row, s) holds global 16B-slot s ^ ((row>>1)&3).
// MODE 0..5 as documented in previous rounds.
template<int MODE, int NS = 1>
__global__ __launch_bounds__(256) void gemm_mfma(
    const __hip_bfloat16* __restrict__ A, const __hip_bfloat16* __restrict__ Bt,
    const float* __restrict__ bias, void* __restrict__ Cv,
    int M, int N, int Kd,
    const int* __restrict__ bucket, const int* __restrict__ cnts,
    const int* __restrict__ bases, const float* __restrict__ residual,
    const float* __restrict__ bias_k, const float* __restrict__ bias_v,
    void* __restrict__ Ck, void* __restrict__ Cv2)
{
    int Me = M;
    const int* rowIdx = nullptr;
    int hbase = 0;
    int ksplit = 0;
    int zsel = 0;
    if (MODE == 2 || MODE == 3) {
        int e = (NS == 2) ? (blockIdx.z >> 1) : blockIdx.z;
        if (NS == 2) ksplit = blockIdx.z & 1;
        Me = cnts[e];
        hbase = bases[e];
        Bt += (size_t)e * N * Kd;
        bias += (size_t)e * N;
        if (MODE == 2) rowIdx = bucket + e * Tt;
        if (MODE == 3) A += (size_t)hbase * Kd;
    }
    if (MODE == 5) {
        zsel = blockIdx.z;
        Bt += (size_t)zsel * Dd * Dd;
        if (zsel == 1) bias = bias_k;
        if (zsel == 2) bias = bias_v;
    }
    int m0 = blockIdx.y * 128;
    if (m0 >= Me) return;
    int n0 = blockIdx.x * 128;

    __shared__ __hip_bfloat16 As[2 * 128 * 32];
    __shared__ __hip_bfloat16 Bs[2 * 128 * 32];

    int tid = threadIdx.x;
    int lane = tid & 63, wave = tid >> 6;
    int wm = (wave & 1) * 64, wn = (wave >> 1) * 64;
    int quad = lane >> 4, l16 = lane & 15;

    int rs = lane >> 2;
    int sslot = (lane & 3) ^ ((lane >> 3) & 3);
    int rowS0 = 16 * (2 * wave + 0) + rs;
    int rowS1 = 16 * (2 * wave + 1) + rs;

    const __hip_bfloat16 *gA0, *gA1;
    if (MODE == 2) {
        int g0 = m0 + rowS0, g1 = m0 + rowS1;
        int r0 = (g0 < Me) ? rowIdx[g0] : 0;
        int r1 = (g1 < Me) ? rowIdx[g1] : 0;
        gA0 = A + (size_t)r0 * Kd + sslot * 8;
        gA1 = A + (size_t)r1 * Kd + sslot * 8;
    } else {
        gA0 = A + (size_t)(m0 + rowS0) * Kd + sslot * 8;
        gA1 = A + (size_t)(m0 + rowS1) * Kd + sslot * 8;
    }
    const __hip_bfloat16* gB0 = Bt + (size_t)(n0 + rowS0) * Kd + sslot * 8;
    const __hip_bfloat16* gB1 = Bt + (size_t)(n0 + rowS1) * Kd + sslot * 8;

    __hip_bfloat16* lA0 = As + (2 * wave + 0) * 512;
    __hip_bfloat16* lA1 = As + (2 * wave + 1) * 512;
    __hip_bfloat16* lB0 = Bs + (2 * wave + 0) * 512;
    __hip_bfloat16* lB1 = Bs + (2 * wave + 1) * 512;

    int rsw = (l16 >> 1) & 3;
    int rdoff = (quad ^ rsw) * 8;

    float4v acc[4][4];
    #pragma unroll
    for (int i = 0; i < 4; i++)
        #pragma unroll
        for (int j = 0; j < 4; j++) acc[i][j] = (float4v)0.f;

    const int NT = Kd >> 5;
    int t0s = 0, t1s = NT;
    if (NS == 2) { int hlf = NT >> 1; t0s = ksplit * hlf; t1s = t0s + hlf; }

    {
        int ko = t0s << 5;
        glds16(gA0 + ko, lA0);
        glds16(gA1 + ko, lA1);
        glds16(gB0 + ko, lB0);
        glds16(gB1 + ko, lB1);
    }
    __syncthreads();

    int cur = 0;
    for (int t = t0s; t < t1s; t++) {
        if (t + 1 < t1s) {
            int ko = (t + 1) << 5;
            int bo = (cur ^ 1) * 4096;
            glds16(gA0 + ko, lA0 + bo);
            glds16(gA1 + ko, lA1 + bo);
            glds16(gB0 + ko, lB0 + bo);
            glds16(gB1 + ko, lB1 + bo);
        }
        int cb = cur * 4096;
        short8 af[4], bf[4];
        #pragma unroll
        for (int i = 0; i < 4; i++)
            af[i] = *(const short8*)(&As[cb + (wm + i * 16 + l16) * 32 + rdoff]);
        #pragma unroll
        for (int j = 0; j < 4; j++)
            bf[j] = *(const short8*)(&Bs[cb + (wn + j * 16 + l16) * 32 + rdoff]);
        #pragma unroll
        for (int i = 0; i < 4; i++)
            #pragma unroll
            for (int j = 0; j < 4; j++)
                acc[i][j] = __builtin_amdgcn_mfma_f32_16x16x32_bf16(af[i], bf[j], acc[i][j], 0, 0, 0);
        __syncthreads();
        cur ^= 1;
    }

    #pragma unroll
    for (int i = 0; i < 4; i++) {
        #pragma unroll
        for (int j = 0; j < 4; j++) {
            int col = n0 + wn + j * 16 + l16;
            float bsv = (MODE == 3 && NS == 2 && ksplit == 1) ? 0.f : bias[col];
            if (MODE == 4 || (MODE == 5 && zsel == 2)) {
                __hip_bfloat16* vt = (__hip_bfloat16*)((MODE == 5) ? Cv2 : Cv);
                int mb = m0 + wm + i * 16 + quad * 4;
                int b = mb >> 11, s0 = mb & (Ss - 1);
                int h = col >> 6, d = col & (DH - 1);
                short4v pk;
                #pragma unroll
                for (int r = 0; r < 4; r++) pk[r] = f2bf(acc[i][j][r] + bsv);
                *(short4v*)(vt + ((size_t)(b * Hh + h) * DH + d) * Ss + s0) = pk;
                continue;
            }
            #pragma unroll
            for (int r = 0; r < 4; r++) {
                int m = m0 + wm + i * 16 + quad * 4 + r;
                if (m >= Me) continue;
                float val = acc[i][j][r] + bsv;
                if (MODE == 0) {
                    ((__hip_bfloat16*)Cv)[(size_t)m * N + col] = __float2bfloat16(val);
                } else if (MODE == 5) {
                    __hip_bfloat16* co = (__hip_bfloat16*)((zsel == 0) ? Cv : Ck);
                    co[(size_t)m * N + col] = __float2bfloat16(val);
                } else if (MODE == 1) {
                    ((float*)Cv)[(size_t)m * N + col] = val + residual[(size_t)m * N + col];
                } else if (MODE == 2) {
                    float z = 0.7978845608028654f * (val + 0.044715f * val * val * val);
                    float eg = __expf(2.f * z);
                    float th = 1.f - __fdividef(2.f, eg + 1.f);
                    ((__hip_bfloat16*)Cv)[(size_t)(hbase + m) * N + col] =
                        __float2bfloat16(0.5f * val * (1.f + th));
                } else { // MODE 3
                    float* o3 = (float*)((NS == 2 && ksplit == 1) ? Cv2 : Cv);
                    o3[(size_t)(hbase + m) * N + col] = val;
                }
            }
        }
    }
}

// ---------------------------------------------------------------------------
// MFMA flash attention, double-buffered LDS K/V, ONE barrier per key-step:
// iteration st writes step st+1's data into buf^1 while computing buf; the
// end-of-iteration barrier separates this iteration's readers of buf[cur]
// from next iteration's writers of buf[cur] (same discipline as GEMM dbuf).
// Block = 4 waves x 16 queries. + T5 setprio. Grid = (h, tile, b).
#define KSZ (32 * 72)
#define VSZ (64 * 40)
__global__ __launch_bounds__(256) void attn_mfma(const __hip_bfloat16* __restrict__ q,
                                                 const __hip_bfloat16* __restrict__ k,
                                                 const __hip_bfloat16* __restrict__ Vt,
                                                 __hip_bfloat16* __restrict__ out) {
    int h = blockIdx.x, tile = blockIdx.y, b = blockIdx.z;
    int wave = threadIdx.x >> 6, lane = threadIdx.x & 63;
    int quad = lane >> 4, l16 = lane & 15;
    int q0 = tile * 64 + wave * 16;
    int tb = b * Ss;

    __shared__ __hip_bfloat16 Ks[2 * KSZ];   // [buf][key][0..63], stride 72
    __shared__ __hip_bfloat16 Vs[2 * VSZ];   // [buf][d][0..31],  stride 40

    const __hip_bfloat16* qp = q + (size_t)(tb + q0 + l16) * (Hh * DH) + h * DH + quad * 8;
    short8 qf0 = *(const short8*)(qp);
    short8 qf1 = *(const short8*)(qp + 32);

    float4v oc[4];
    #pragma unroll
    for (int i = 0; i < 4; i++) oc[i] = (float4v)0.f;
    float lsum = 0.f;

    const __hip_bfloat16* kbase = k + (size_t)tb * (Hh * DH) + h * DH;
    const __hip_bfloat16* vbase = Vt + ((size_t)(b * Hh + h) * DH) * Ss;
    int qglob = q0 + l16;
    int srcA = (quad & 1) * 32 + l16;
    int srcB = srcA + 16;
    int sel = quad >> 1;
    int nsteps = 2 * tile + 2;

    int krow = threadIdx.x >> 3, kg = threadIdx.x & 7;   // K stage: 32 rows x 8x16B
    int vd   = threadIdx.x >> 2, vg = threadIdx.x & 3;   // V stage: 64 rows x 4x16B
    int kslot = krow * 72 + kg * 8;
    int vslot = vd * 40 + vg * 8;

    // prologue: stage step 0 into buf 0; prefetch step-1 regs
    short8 kv = *(const short8*)(kbase + (size_t)krow * (Hh * DH) + kg * 8);
    short8 vv = *(const short8*)(vbase + (size_t)vd * Ss + vg * 8);
    *(short8*)(&Ks[kslot]) = kv;
    *(short8*)(&Vs[vslot]) = vv;
    __syncthreads();
    if (nsteps > 1) {
        kv = *(const short8*)(kbase + (size_t)(32 + krow) * (Hh * DH) + kg * 8);
        vv = *(const short8*)(vbase + (size_t)vd * Ss + 32 + vg * 8);
    }

    for (int st = 0; st < nsteps; st++) {
        int k0 = st * 32;
        int cur = st & 1;
        int kb = cur * KSZ, vb = cur * VSZ;
        // write step st+1 into the other buffer (no readers this iteration)
        if (st + 1 < nsteps) {
            int kn = (cur ^ 1) * KSZ, vn = (cur ^ 1) * VSZ;
            *(short8*)(&Ks[kn + kslot]) = kv;
            *(short8*)(&Vs[vn + vslot]) = vv;
        }
        // issue global loads for step st+2 (latency hides under compute)
        if (st + 2 < nsteps) {
            kv = *(const short8*)(kbase + (size_t)(k0 + 64 + krow) * (Hh * DH) + kg * 8);
            vv = *(const short8*)(vbase + (size_t)vd * Ss + (k0 + 64) + vg * 8);
        }

        short8 a0 = *(const short8*)(&Ks[kb + l16 * 72 + quad * 8]);
        short8 a1 = *(const short8*)(&Ks[kb + l16 * 72 + 32 + quad * 8]);
        short8 a2 = *(const short8*)(&Ks[kb + (l16 + 16) * 72 + quad * 8]);
        short8 a3 = *(const short8*)(&Ks[kb + (l16 + 16) * 72 + 32 + quad * 8]);

        float4v c0 = (float4v)0.f, c1 = (float4v)0.f;
        __builtin_amdgcn_s_setprio(1);
        c0 = __builtin_amdgcn_mfma_f32_16x16x32_bf16(a0, qf0, c0, 0, 0, 0);
        c0 = __builtin_amdgcn_mfma_f32_16x16x32_bf16(a1, qf1, c0, 0, 0, 0);
        c1 = __builtin_amdgcn_mfma_f32_16x16x32_bf16(a2, qf0, c1, 0, 0, 0);
        c1 = __builtin_amdgcn_mfma_f32_16x16x32_bf16(a3, qf1, c1, 0, 0, 0);
        __builtin_amdgcn_s_setprio(0);

        float p0[4], p1[4];
        #pragma unroll
        for (int r = 0; r < 4; r++) {
            int key0 = k0 + quad * 4 + r;
            int key1 = key0 + 16;
            p0[r] = (key0 <= qglob) ? __expf(c0[r] * 0.125f - 4.f) : 0.f;
            p1[r] = (key1 <= qglob) ? __expf(c1[r] * 0.125f - 4.f) : 0.f;
            lsum += p0[r] + p1[r];
        }

        short8 pf;
        #pragma unroll
        for (int r = 0; r < 4; r++) {
            float t0 = __shfl(p0[r], srcA), t1 = __shfl(p1[r], srcA);
            pf[r] = f2bf(sel ? t1 : t0);
            float u0 = __shfl(p0[r], srcB), u1 = __shfl(p1[r], srcB);
            pf[4 + r] = f2bf(sel ? u1 : u0);
        }

        __builtin_amdgcn_s_setprio(1);
        #pragma unroll
        for (int nt = 0; nt < 4; nt++) {
            short8 bv = *(const short8*)(&Vs[vb + (nt * 16 + l16) * 40 + quad * 8]);
            oc[nt] = __builtin_amdgcn_mfma_f32_16x16x32_bf16(pf, bv, oc[nt], 0, 0, 0);
        }
        __builtin_amdgcn_s_setprio(0);
        __syncthreads();   // single barrier per step
    }

    lsum += __shfl_xor(lsum, 16);
    lsum += __shfl_xor(lsum, 32);
    float linv[4];
    #pragma unroll
    for (int r = 0; r < 4; r++) linv[r] = 1.f / __shfl(lsum, quad * 4 + r);

    #pragma unroll
    for (int nt = 0; nt < 4; nt++) {
        #pragma unroll
        for (int r = 0; r < 4; r++) {
            int tokq = tb + q0 + quad * 4 + r;
            out[(size_t)tokq * (Hh * DH) + h * DH + nt * 16 + l16] =
                __float2bfloat16(oc[nt][r] * linv[r]);
        }
    }
}

// ---------------------------------------------------------------------------
// Gate: inline fp32 LN2 + softmax + top-2, block-aggregated atomics.
// Also WRITES ffn_in = bf16(LN2(working)) (round-14 verified fusion).
#define GT 64   // tokens per block
__global__ __launch_bounds__(256) void gate_kernel(const float* __restrict__ wk,
                                                   const float* __restrict__ g2s,
                                                   const float* __restrict__ g2b,
                                                   const float* __restrict__ Wg,
                                                   const float* __restrict__ bg,
                                                   __hip_bfloat16* __restrict__ ffn,
                                                   float* __restrict__ psum,
                                                   int* __restrict__ counts,
                                                   int* __restrict__ bucket,
                                                   int* __restrict__ eidx,
                                                   int* __restrict__ epos,
                                                   float* __restrict__ ew) {
    int t0 = blockIdx.x * GT;
    int wave = threadIdx.x >> 6, lane = threadIdx.x & 63;

    __shared__ float sp[GT][Ee];
    __shared__ int   sel_e[2][GT];
    __shared__ int   spos[2][GT];
    __shared__ int   lbase[Ee];

    for (int i = wave; i < GT; i += 4) {
        int t = t0 + i;
        const float* xr = wk + (size_t)t * Dd;
        __hip_bfloat16* yr = ffn + (size_t)t * Dd;
        float xv[16];
        float s1 = 0.f, sq = 0.f;
        #pragma unroll
        for (int j = 0; j < 16; j++) {
            float v = xr[lane + j * 64];
            xv[j] = v; s1 += v; sq += v * v;
        }
        #pragma unroll
        for (int off = 32; off; off >>= 1) { s1 += __shfl_xor(s1, off); sq += __shfl_xor(sq, off); }
        float mu = s1 * (1.f / Dd), var = sq * (1.f / Dd) - mu * mu;
        float rstd = rsqrtf(var + 1e-6f);
        float acc[Ee] = {};
        #pragma unroll
        for (int j = 0; j < 16; j++) {
            int d = lane + j * 64;
            float xn = (xv[j] - mu) * rstd * g2s[d] + g2b[d];
            yr[d] = __float2bfloat16(xn);            // fused ffn_in write
            const float* wr = Wg + d * Ee;
            #pragma unroll
            for (int e = 0; e < Ee; e++) acc[e] += xn * wr[e];
        }
        #pragma unroll
        for (int e = 0; e < Ee; e++)
            #pragma unroll
            for (int off = 32; off; off >>= 1) acc[e] += __shfl_xor(acc[e], off);
        if (lane == 0) {
            float lg[Ee], mx = -1e30f;
            #pragma unroll
            for (int e = 0; e < Ee; e++) { lg[e] = acc[e] + bg[e]; mx = fmaxf(mx, lg[e]); }
            float p[Ee], ssum = 0.f;
            #pragma unroll
            for (int e = 0; e < Ee; e++) { p[e] = __expf(lg[e] - mx); ssum += p[e]; }
            float ise = 1.f / ssum;
            #pragma unroll
            for (int e = 0; e < Ee; e++) { p[e] *= ise; sp[i][e] = p[e]; }
            int e1 = 0;
            for (int e = 1; e < Ee; e++) if (p[e] > p[e1]) e1 = e;
            int e2 = -1;
            for (int e = 0; e < Ee; e++) if (e != e1 && (e2 < 0 || p[e] > p[e2])) e2 = e;
            sel_e[0][i] = e1; sel_e[1][i] = e2;
            float w1 = p[e1], w2 = p[e2], isw = 1.f / (w1 + w2);
            eidx[2 * t] = e1; ew[2 * t] = w1 * isw;
            eidx[2 * t + 1] = e2; ew[2 * t + 1] = w2 * isw;
        }
    }
    __syncthreads();

    if (threadIdx.x < Ee) {
        int e = threadIdx.x;
        int local = 0;
        for (int i = 0; i < GT; i++) {
            if (sel_e[0][i] == e) spos[0][i] = local++;
            if (sel_e[1][i] == e) spos[1][i] = local++;
        }
        lbase[e] = atomicAdd(&counts[e], local);
        float ps = 0.f;
        for (int i = 0; i < GT; i++) ps += sp[i][e];
        atomicAdd(&psum[e], ps);
    }
    __syncthreads();

    if (threadIdx.x < GT) {
        int i = threadIdx.x, t = t0 + i;
        #pragma unroll
        for (int s = 0; s < 2; s++) {
            int e = sel_e[s][i];
            int pos = lbase[e] + spos[s][i];
            bucket[e * Tt + pos] = t;
            epos[2 * t + s] = pos;
        }
    }
}

__global__ void prefix_kernel(const int* counts, int* bases) {
    if (threadIdx.x == 0) {
        int run = 0;
        for (int e = 0; e < Ee; e++) { bases[e] = run; run += counts[e]; }
    }
}

// out[t] = working[t] + w0*(P0[slot0]{+P1[slot0]}) + w1*(P0[slot1]{+P1[slot1]})
__global__ __launch_bounds__(256) void combine_out(const float* __restrict__ working,
                                                   const float* __restrict__ O2,
                                                   const float* __restrict__ O2b,
                                                   const int* __restrict__ bases,
                                                   const int* __restrict__ eidx,
                                                   const int* __restrict__ epos,
                                                   const float* __restrict__ ew,
                                                   float* __restrict__ out,
                                                   int ns) {
    int t = blockIdx.x, tid = threadIdx.x;
    int e0 = eidx[2 * t], e1 = eidx[2 * t + 1];
    size_t r0 = (size_t)(bases[e0] + epos[2 * t]) * Dd;
    size_t r1 = (size_t)(bases[e1] + epos[2 * t + 1]) * Dd;
    float w0 = ew[2 * t], w1 = ew[2 * t + 1];
    const float4* wr = (const float4*)(working + (size_t)t * Dd);
    const float4* o0 = (const float4*)(O2 + r0);
    const float4* o1 = (const float4*)(O2 + r1);
    float4 a = wr[tid], x0 = o0[tid], x1 = o1[tid];
    if (ns == 2) {
        const float4* p0 = (const float4*)(O2b + r0);
        const float4* p1 = (const float4*)(O2b + r1);
        float4 y0 = p0[tid], y1 = p1[tid];
        x0.x += y0.x; x0.y += y0.y; x0.z += y0.z; x0.w += y0.w;
        x1.x += y1.x; x1.y += y1.y; x1.z += y1.z; x1.w += y1.w;
    }
    float4* dst = (float4*)(out + (size_t)t * Dd);
    dst[tid] = make_float4(a.x + w0 * x0.x + w1 * x1.x,
                           a.y + w0 * x0.y + w1 * x1.y,
                           a.z + w0 * x0.z + w1 * x1.z,
                           a.w + w0 * x0.w + w1 * x1.w);
}

__global__ void aux_kernel(const int* counts, const float* psum, float* out) {
    if (threadIdx.x == 0 && blockIdx.x == 0) {
        float a = 0.f;
        for (int e = 0; e < Ee; e++)
            a += (counts[e] * (1.f / Tt)) * (psum[e] * (1.f / Tt));
        out[0] = 0.01f * (float)Ee * a;
    }
}

// ---------------------------------------------------------------------------
extern "C" void kernel_launch(void* const* d_in, const int* in_sizes, int n_in,
                              void* d_out, int out_size, void* d_ws, size_t ws_size,
                              hipStream_t stream) {
    const float* x     = (const float*)d_in[0];
    const float* ln1_s = (const float*)d_in[1];
    const float* ln1_b = (const float*)d_in[2];
    const float* Wq    = (const float*)d_in[3];
    const float* bq    = (const float*)d_in[4];
    const float* Wk    = (const float*)d_in[5];
    const float* bk    = (const float*)d_in[6];
    const float* Wv    = (const float*)d_in[7];
    const float* bv    = (const float*)d_in[8];
    const float* Wo    = (const float*)d_in[9];
    const float* bo    = (const float*)d_in[10];
    const float* ln2_s = (const float*)d_in[11];
    const float* ln2_b = (const float*)d_in[12];
    const float* Wg    = (const float*)d_in[13];
    const float* bg    = (const float*)d_in[14];
    const float* W1    = (const float*)d_in[15];
    const float* b1    = (const float*)d_in[16];
    const float* W2    = (const float*)d_in[17];
    const float* b2    = (const float*)d_in[18];

    const size_t MBy = 1u << 20;
    char* base = (char*)d_ws;
    __hip_bfloat16* attn_in = (__hip_bfloat16*)(base);             // 0-8   (also attn_out)
    __hip_bfloat16* qbf     = (__hip_bfloat16*)(base + 8 * MBy);   // 8-16
    __hip_bfloat16* kbf     = (__hip_bfloat16*)(base + 16 * MBy);  // 16-24
    __hip_bfloat16* Vt      = (__hip_bfloat16*)(base + 24 * MBy);  // 24-32
    float*          working = (float*)(base + 32 * MBy);           // 32-48
    __hip_bfloat16* ffn_in  = (__hip_bfloat16*)(base + 48 * MBy);  // 48-56
    __hip_bfloat16* Hbuf    = (__hip_bfloat16*)(base + 56 * MBy);  // 56-120 (8192x4096 bf16)
    float*          O2      = (float*)(base);                      // 0-32  (overlays dead attn bufs)
    __hip_bfloat16* WT      = (__hip_bfloat16*)(base + 120 * MBy); // 120-184 shared (W1T then W2T)
    __hip_bfloat16* WqT     = (__hip_bfloat16*)(base + 120 * MBy); // QKVO transposes (dead before WT)
    __hip_bfloat16* WkT     = (__hip_bfloat16*)(base + 122 * MBy);
    __hip_bfloat16* WvT     = (__hip_bfloat16*)(base + 124 * MBy);
    __hip_bfloat16* WoT     = (__hip_bfloat16*)(base + 126 * MBy);
    char* rt = base + 184 * MBy;
    int*   bucket = (int*)rt;                        // 8*4096 ints
    int*   counts = (int*)(rt + Ee * Tt * 4);
    int*   bases  = counts + 64;
    float* psum   = (float*)(bases + 64);
    int*   eidx   = (int*)(psum + 64);               // 2*Tt
    int*   epos   = eidx + 2 * Tt;
    float* ew     = (float*)(epos + 2 * Tt);

    // split-K second partial buffer (only if workspace permits)
    bool   sk  = (ws_size >= (size_t)224 * MBy);
    float* O2b = sk ? (float*)(base + 192 * MBy) : O2;

    float* out  = (float*)d_out;
    float* auxp = out + (size_t)Tt * Dd;

    // transpose_qkvo block (0,0,0) zeroes psum/counts (replaces zero_init)
    transpose_qkvo<<<dim3(Dd / 64, Dd / 64, 4), 256, 0, stream>>>(
        Wq, Wk, Wv, Wo, WqT, WkT, WvT, WoT, psum, counts);
    ln_kernel<<<Tt, 256, 0, stream>>>(x, ln1_s, ln1_b, attn_in);

    dim3 gqkv(Dd / 128, Tt / 128);
    // fused QKV: z=0 -> qbf, z=1 -> kbf, z=2 -> Vt (transposed)
    gemm_mfma<5><<<dim3(Dd / 128, Tt / 128, 3), 256, 0, stream>>>(
        attn_in, WqT, bq, qbf, Tt, Dd, Dd,
        nullptr, nullptr, nullptr, nullptr, bk, bv, kbf, Vt);

    attn_mfma<<<dim3(Hh, Ss / 64, Bb), 256, 0, stream>>>(qbf, kbf, Vt, attn_in);

    gemm_mfma<1><<<gqkv, 256, 0, stream>>>(attn_in, WoT, bo, working, Tt, Dd, Dd,
                                           nullptr, nullptr, nullptr, x,
                                           nullptr, nullptr, nullptr, nullptr);

    // gate computes LN2 inline and writes ffn_in (replaces second ln_kernel)
    gate_kernel<<<Tt / GT, 256, 0, stream>>>(working, ln2_s, ln2_b, Wg, bg, ffn_in,
                                             psum, counts, bucket, eidx, epos, ew);
    prefix_kernel<<<1, 64, 0, stream>>>(counts, bases);

    transpose_we<<<dim3(FH / 64, Dd / 64, Ee), 256, 0, stream>>>(W1, WT, Dd, FH);
    gemm_mfma<2><<<dim3(FH / 128, Tt / 128, Ee), 256, 0, stream>>>(
        ffn_in, WT, b1, Hbuf, Tt, FH, Dd, bucket, counts, bases, nullptr,
        nullptr, nullptr, nullptr, nullptr);
    transpose_we<<<dim3(Dd / 64, FH / 64, Ee), 256, 0, stream>>>(W2, WT, FH, Dd);
    if (sk) {
        gemm_mfma<3, 2><<<dim3(Dd / 128, Tt / 128, 2 * Ee), 256, 0, stream>>>(
            Hbuf, WT, b2, O2, Tt, Dd, FH, bucket, counts, bases, nullptr,
            nullptr, nullptr, nullptr, O2b);
    } else {
        gemm_mfma<3, 1><<<dim3(Dd / 128, Tt / 128, Ee), 256, 0, stream>>>(
            Hbuf, WT, b2, O2, Tt, Dd, FH, bucket, counts, bases, nullptr,
            nullptr, nullptr, nullptr, nullptr);
    }

    combine_out<<<Tt, 256, 0, stream>>>(working, O2, O2b, bases, eidx, epos, ew, out,
                                        sk ? 2 : 1);
    aux_kernel<<<1, 64, 0, stream>>>(counts, psum, auxp);
}